// Round 14
// baseline (214.246 us; speedup 1.0000x reference)
//
#include <hip/hip_runtime.h>
#include <hip/hip_bf16.h>
#include <hip/hip_fp16.h>

// TextEncoderBlock R14: attn grid 2048->4320 (1 item/block, 4 waves/SIMD),
// pointer-increment staging in all GEMM k-loops (kills per-step 64b addr
// recompute). Otherwise identical to R13 (best: 214us).
// B=1 L=2048 EMBD=960 FFN=2560 QH=15 KVH=5 HD=64

typedef __hip_bfloat16 bf16;
typedef __attribute__((ext_vector_type(8))) short bf16x8;
typedef __attribute__((ext_vector_type(4))) float f32x4;
typedef __attribute__((ext_vector_type(16))) float f32x16;

#define EPS 1.1920929e-07f
#define QSCL 0.1803368801111f  /* 0.125 * log2(e) */

__device__ __forceinline__ void gload_lds16(const bf16* g, bf16* l) {
  __builtin_amdgcn_global_load_lds(
      (const __attribute__((address_space(1))) unsigned int*)g,
      (__attribute__((address_space(3))) unsigned int*)l, 16, 0, 0);
}

__device__ __forceinline__ unsigned short f2bfu(float f) {
  __hip_bfloat16 b = __float2bfloat16(f);
  return *reinterpret_cast<unsigned short*>(&b);
}
__device__ __forceinline__ float bfu2f(unsigned short u) {
  return __uint_as_float(((unsigned int)u) << 16);
}
__device__ __forceinline__ float hu2f(unsigned short u) {
  __half_raw r; r.x = u;
  return __half2float((__half)r);
}
__device__ __forceinline__ unsigned int cvtpk(float lo, float hi_) {
  unsigned int r;
  asm("v_cvt_pk_bf16_f32 %0, %1, %2" : "=v"(r) : "v"(lo), "v"(hi_));
  return r;
}

// ---------------- shared 128x128 GEMM core (BK=32, dbuf, ptr-increment) -----
__device__ __forceinline__ void gemm_core128(const bf16* __restrict__ A,
    const bf16* __restrict__ BT, int K, int ks0, int ks1, int m0, int n0,
    bf16 (&sA)[2][4096], bf16 (&sB)[2][4096], f32x4 (&acc)[4][4]) {
  const int t = threadIdx.x, w = t >> 6, lane = t & 63;
  const int lg = lane >> 4, lr = lane & 15;
  const int wm = w >> 1, wn = w & 1;
  const int c0 = w * 128 + lane;
  const int c1 = c0 + 64;
  const bf16* pA0 = A + (size_t)(m0 + (c0 >> 2)) * K + ks0 * 32 + (c0 & 3) * 8;
  const bf16* pA1 = A + (size_t)(m0 + (c1 >> 2)) * K + ks0 * 32 + (c1 & 3) * 8;
  const bf16* pB0 = BT + (size_t)(n0 + (c0 >> 2)) * K + ks0 * 32 + (c0 & 3) * 8;
  const bf16* pB1 = BT + (size_t)(n0 + (c1 >> 2)) * K + ks0 * 32 + (c1 & 3) * 8;
  bf16* const dA0[2] = {&sA[0][c0 * 8], &sA[1][c0 * 8]};
  bf16* const dA1[2] = {&sA[0][c1 * 8], &sA[1][c1 * 8]};
  bf16* const dB0[2] = {&sB[0][c0 * 8], &sB[1][c0 * 8]};
  bf16* const dB1[2] = {&sB[0][c1 * 8], &sB[1][c1 * 8]};
  auto stage = [&](int buf) {
    gload_lds16(pA0, dA0[buf]);
    gload_lds16(pA1, dA1[buf]);
    gload_lds16(pB0, dB0[buf]);
    gload_lds16(pB1, dB1[buf]);
    pA0 += 32; pA1 += 32; pB0 += 32; pB1 += 32;
  };
  stage(0);
  __syncthreads();
  int cur = 0;
  for (int ks = ks0; ks < ks1; ++ks) {
    if (ks + 1 < ks1) stage(cur ^ 1);
    bf16x8 af[4], bfr[4];
#pragma unroll
    for (int mi = 0; mi < 4; ++mi)
      af[mi] = *reinterpret_cast<const bf16x8*>(&sA[cur][(wm * 64 + mi * 16 + lr) * 32 + lg * 8]);
#pragma unroll
    for (int ni = 0; ni < 4; ++ni)
      bfr[ni] = *reinterpret_cast<const bf16x8*>(&sB[cur][(wn * 64 + ni * 16 + lr) * 32 + lg * 8]);
#pragma unroll
    for (int mi = 0; mi < 4; ++mi)
#pragma unroll
      for (int ni = 0; ni < 4; ++ni)
        acc[mi][ni] = __builtin_amdgcn_mfma_f32_16x16x32_bf16(af[mi], bfr[ni], acc[mi][ni], 0, 0, 0);
    __syncthreads();
    cur ^= 1;
  }
}

// ---------------- fused prep: transposes + rope + items + first rmsnorm -----
__device__ void do_transpose(float (*tile)[65], const float* __restrict__ W,
                             bf16* __restrict__ WT, int K, int N, int bx, int by,
                             int map) {
  const int k0 = by * 64, n0 = bx * 64;
  const int tx = threadIdx.x & 63, ty = threadIdx.x >> 6;
#pragma unroll
  for (int i = 0; i < 16; ++i) {
    int r = ty + i * 4;
    tile[r][tx] = W[(size_t)(k0 + r) * N + n0 + tx];
  }
  __syncthreads();
#pragma unroll
  for (int i = 0; i < 16; ++i) {
    int r = ty + i * 4;
    int v = n0 + r;
    int row = (map == 0) ? v : ((v >> 4) << 5) + (v & 15) + (map == 2 ? 16 : 0);
    WT[(size_t)row * K + k0 + tx] = __float2bfloat16(tile[tx][r]);
  }
}

__launch_bounds__(256)
__global__ void prep2_k(const float* __restrict__ wq, const float* __restrict__ wk,
                        const float* __restrict__ wv, const float* __restrict__ wo,
                        const float* __restrict__ wg, const float* __restrict__ wu,
                        const float* __restrict__ wd, bf16* __restrict__ wqkvT,
                        bf16* __restrict__ woT, bf16* __restrict__ wguT,
                        bf16* __restrict__ wdT, float2* __restrict__ cstab,
                        int* __restrict__ items, const float* __restrict__ x,
                        const float* __restrict__ g1, bf16* __restrict__ nb) {
  __shared__ float tile[64][65];
  int b = blockIdx.x;
  if (b < 225) {
    do_transpose(tile, wq, wqkvT, 960, 960, b % 15, b / 15, 0);
  } else if (b < 300) {
    b -= 225;
    do_transpose(tile, wk, wqkvT + 921600, 960, 320, b % 5, b / 5, 0);
  } else if (b < 375) {
    b -= 300;
    do_transpose(tile, wv, wqkvT + 1228800, 960, 320, b % 5, b / 5, 0);
  } else if (b < 600) {
    b -= 375;
    do_transpose(tile, wo, woT, 960, 960, b % 15, b / 15, 0);
  } else if (b < 1200) {
    b -= 600;
    do_transpose(tile, wg, wguT, 960, 2560, b % 40, b / 40, 1);
  } else if (b < 1800) {
    b -= 1200;
    do_transpose(tile, wu, wguT, 960, 2560, b % 40, b / 40, 2);
  } else if (b < 2400) {
    b -= 1800;
    do_transpose(tile, wd, wdT, 2560, 960, b % 15, b / 15, 0);
  } else if (b < 2656) {
    const int idx = (b - 2400) * 256 + threadIdx.x;
    const int pos = idx >> 5, d = idx & 31;
    float inv = powf(10000.f, -(float)d * (1.f / 32.f));
    float rad = (float)pos * inv;
    cstab[idx] = make_float2(cosf(rad), sinf(rad));
  } else if (b < 2660) {
    const int idx = (b - 2656) * 256 + threadIdx.x;
    if (idx < 960) {
      const int head = idx >> 6, qt = idx & 63;
      const int a = qt >> 3, bq = qt & 7;
      const int psum = qt + 8 * (a * (a - 1) / 2) + a * bq;
      const int base = head * 288 + psum;
      const int nch = (qt >> 3) + 1;
      for (int c = 0; c < nch; ++c)
        items[base + c] = qt | (head << 8) | (c << 16);
    }
  } else {
    const int row = b - 2660;
    const float* xr = x + (size_t)row * 960;
    const int t = threadIdx.x;
    float4 v = {0.f, 0.f, 0.f, 0.f};
    float ss = 0.f;
    if (t < 240) {
      v = *reinterpret_cast<const float4*>(&xr[t * 4]);
      ss = v.x * v.x + v.y * v.y + v.z * v.z + v.w * v.w;
    }
#pragma unroll
    for (int off = 32; off; off >>= 1) ss += __shfl_down(ss, off);
    __shared__ float red[4];
    __shared__ float s_scale;
    if ((t & 63) == 0) red[t >> 6] = ss;
    __syncthreads();
    if (t == 0) {
      float tot = red[0] + red[1] + red[2] + red[3];
      s_scale = rsqrtf(tot * (1.f / 960.f) + EPS);
    }
    __syncthreads();
    if (t < 240) {
      const float sc = s_scale;
      const float4 gv = *reinterpret_cast<const float4*>(&g1[t * 4]);
      ushort4 o;
      o.x = f2bfu(v.x * sc * gv.x);
      o.y = f2bfu(v.y * sc * gv.y);
      o.z = f2bfu(v.z * sc * gv.z);
      o.w = f2bfu(v.w * sc * gv.w);
      *reinterpret_cast<ushort4*>(&nb[(size_t)row * 960 + t * 4]) = o;
    }
  }
}

// ---------------- rmsfuse2: out=sum(P)+x (residual2); dual norm; kv zero ----
__launch_bounds__(256)
__global__ void rmsfuse2_k(const __half* __restrict__ P, const float* __restrict__ x,
                           const float* __restrict__ g1, const float* __restrict__ g2,
                           float* __restrict__ outp, bf16* __restrict__ nbF,
                           bf16* __restrict__ nbK) {
  if (blockIdx.x >= 2048) {
    const int zb = blockIdx.x - 2048;
    for (int i = zb * 256 + threadIdx.x; i < 327680; i += 131072) {
      float4 z = {0.f, 0.f, 0.f, 0.f};
      *reinterpret_cast<float4*>(&outp[1966080 + (size_t)i * 4]) = z;
    }
    return;
  }
  const int row = blockIdx.x;
  const int t = threadIdx.x;
  float4 v = {0.f, 0.f, 0.f, 0.f};
  float ss = 0.f;
  if (t < 240) {
    const size_t e = (size_t)row * 960 + t * 4;
    v = *reinterpret_cast<const float4*>(&x[e]);
#pragma unroll
    for (int s = 0; s < 4; ++s) {
      ushort4 pa = *reinterpret_cast<const ushort4*>(&P[(size_t)s * 1966080 + e]);
      v.x += hu2f(pa.x); v.y += hu2f(pa.y); v.z += hu2f(pa.z); v.w += hu2f(pa.w);
    }
    ss = v.x * v.x + v.y * v.y + v.z * v.z + v.w * v.w;
  }
#pragma unroll
  for (int off = 32; off; off >>= 1) ss += __shfl_down(ss, off);
  __shared__ float red[4];
  __shared__ float s_scale;
  if ((t & 63) == 0) red[t >> 6] = ss;
  __syncthreads();
  if (t == 0) {
    float tot = red[0] + red[1] + red[2] + red[3];
    s_scale = rsqrtf(tot * (1.f / 960.f) + EPS);
  }
  __syncthreads();
  if (t < 240) {
    const size_t e = (size_t)row * 960 + t * 4;
    const float sc = s_scale;
    *reinterpret_cast<float4*>(&outp[e]) = v;
    const float4 gv2 = *reinterpret_cast<const float4*>(&g2[t * 4]);
    const float4 gv1 = *reinterpret_cast<const float4*>(&g1[t * 4]);
    ushort4 oF, oK;
    oF.x = f2bfu(v.x * sc * gv2.x); oF.y = f2bfu(v.y * sc * gv2.y);
    oF.z = f2bfu(v.z * sc * gv2.z); oF.w = f2bfu(v.w * sc * gv2.w);
    oK.x = f2bfu(v.x * sc * gv1.x); oK.y = f2bfu(v.y * sc * gv1.y);
    oK.z = f2bfu(v.z * sc * gv1.z); oK.w = f2bfu(v.w * sc * gv1.w);
    *reinterpret_cast<ushort4*>(&nbF[e]) = oF;
    *reinterpret_cast<ushort4*>(&nbK[e]) = oK;
  }
}

// ---------------- FFN GEMM 128x128 (natural dispatch), SwiGLU epilogue ------
__launch_bounds__(256)
__global__ void gemm_ffn(const bf16* __restrict__ A, const bf16* __restrict__ BT,
                         bf16* __restrict__ actb) {
  __shared__ __align__(16) bf16 sA[2][4096];
  __shared__ __align__(16) bf16 sB[2][4096];
  const int t = threadIdx.x, w = t >> 6, lane = t & 63;
  const int lg = lane >> 4, lr = lane & 15;
  const int wm = w >> 1, wn = w & 1;
  const int m0 = blockIdx.y * 128, n0 = blockIdx.x * 128;
  f32x4 acc[4][4] = {};
  gemm_core128(A, BT, 960, 0, 30, m0, n0, sA, sB, acc);

  const int colbase = n0 + wn * 64;
#pragma unroll
  for (int mi = 0; mi < 4; ++mi) {
    const int row = m0 + wm * 64 + mi * 16 + lg * 4;
#pragma unroll
    for (int p = 0; p < 2; ++p) {
      const int oc = ((colbase >> 5) + p) * 16 + lr;
#pragma unroll
      for (int r = 0; r < 4; ++r) {
        float gf = acc[mi][2 * p][r], uf = acc[mi][2 * p + 1][r];
        float s = gf / (1.f + __expf(-gf));
        actb[(size_t)(row + r) * 2560 + oc] = __float2bfloat16(s * uf);
      }
    }
  }
}

// ---------------- split-K GEMM: MODE 0 fp16 partials, MODE 1 atomic out,
//                  MODE 2 atomic kv-split out ------------------------------
template <int MODE>
__launch_bounds__(256)
__global__ void gemm_sk(const bf16* __restrict__ A, const bf16* __restrict__ BT,
                        __half* __restrict__ P, float* __restrict__ Cf,
                        int N, int K, int nsteps, int spl) {
  __shared__ __align__(16) bf16 sA[2][4096];
  __shared__ __align__(16) bf16 sB[2][4096];
  const int nx = gridDim.x, ny = gridDim.y;
  const int total = nx * ny * gridDim.z;
  const int lid = blockIdx.x + nx * (blockIdx.y + ny * blockIdx.z);
  const int cpx = total >> 3;
  const int sid = (lid & 7) * cpx + (lid >> 3);
  const int bx = sid % nx, by = (sid / nx) % ny, bz = sid / (nx * ny);
  const int t = threadIdx.x, w = t >> 6, lane = t & 63;
  const int lg = lane >> 4, lr = lane & 15;
  const int wm = w >> 1, wn = w & 1;
  const int m0 = by * 128, n0 = bx * 128;
  const int ks0 = bz * spl, ks1 = min(ks0 + spl, nsteps);
  f32x4 acc[4][4] = {};
  gemm_core128(A, BT, K, ks0, ks1, m0, n0, sA, sB, acc);

  if (MODE == 0) {
    __half* Ps = P + (size_t)bz * 2048 * N;
#pragma unroll
    for (int mi = 0; mi < 4; ++mi) {
      const int row = m0 + wm * 64 + mi * 16 + lg * 4;
#pragma unroll
      for (int ni = 0; ni < 4; ++ni) {
        const int col = n0 + wn * 64 + ni * 16 + lr;
        if (col < N) {
#pragma unroll
          for (int r = 0; r < 4; ++r)
            Ps[(size_t)(row + r) * N + col] = __float2half(acc[mi][ni][r]);
        }
      }
    }
  } else if (MODE == 1) {
#pragma unroll
    for (int mi = 0; mi < 4; ++mi) {
      const int row = m0 + wm * 64 + mi * 16 + lg * 4;
#pragma unroll
      for (int ni = 0; ni < 4; ++ni) {
        const int col = n0 + wn * 64 + ni * 16 + lr;
        if (col < N) {
#pragma unroll
          for (int r = 0; r < 4; ++r)
            atomicAdd(&Cf[(size_t)(row + r) * N + col], acc[mi][ni][r]);
        }
      }
    }
  } else {  // MODE 2: kv (N=640): cols 0..319 -> k_out, 320..639 -> v_out
#pragma unroll
    for (int mi = 0; mi < 4; ++mi) {
      const int row = m0 + wm * 64 + mi * 16 + lg * 4;
#pragma unroll
      for (int ni = 0; ni < 4; ++ni) {
        const int col = n0 + wn * 64 + ni * 16 + lr;
#pragma unroll
        for (int r = 0; r < 4; ++r) {
          const int rr = row + r;
          float* dst = (col < 320) ? Cf + (size_t)rr * 320 + col
                                   : Cf + 655360 + (size_t)rr * 320 + (col - 320);
          atomicAdd(dst, acc[mi][ni][r]);
        }
      }
    }
  }
}

// ---------------- QKV GEMM 64x128, fused RoPE + fragment-order K/V ----------
__launch_bounds__(256)
__global__ void gemm_qkv(const bf16* __restrict__ A, const bf16* __restrict__ BT,
                         const float2* __restrict__ cstab, bf16* __restrict__ qr,
                         bf16* __restrict__ kr2, bf16* __restrict__ vTb2) {
  const int N = 1600, K = 960;
  __shared__ __align__(16) bf16 sA[2][64 * 32];
  __shared__ __align__(16) bf16 sB[2][128 * 32];
  const int t = threadIdx.x, w = t >> 6, lane = t & 63;
  const int lg = lane >> 4, lr = lane & 15;
  const int wm = w >> 1, wn = w & 1;
  const int m0 = blockIdx.y * 64, n0 = blockIdx.x * 128;
  f32x4 acc[2][4] = {};
  const int nsteps = K / 32;

  // pointer-increment staging: 1 A chunk + 2 B chunks per thread
  const int cA = t, cB0 = t, cB1 = t + 256;
  const bf16* pA = A + (size_t)(m0 + (cA >> 2)) * K + (cA & 3) * 8;
  int brow0 = n0 + (cB0 >> 2); if (brow0 >= N) brow0 = N - 1;
  int brow1 = n0 + (cB1 >> 2); if (brow1 >= N) brow1 = N - 1;
  const bf16* pB0 = BT + (size_t)brow0 * K + (cB0 & 3) * 8;
  const bf16* pB1 = BT + (size_t)brow1 * K + (cB1 & 3) * 8;
  auto stage = [&](int buf) {
    gload_lds16(pA, &sA[buf][cA * 8]);
    gload_lds16(pB0, &sB[buf][cB0 * 8]);
    gload_lds16(pB1, &sB[buf][cB1 * 8]);
    pA += 32; pB0 += 32; pB1 += 32;
  };

  stage(0);
  __syncthreads();
  int cur = 0;
  for (int ks = 0; ks < nsteps; ++ks) {
    if (ks + 1 < nsteps) stage(cur ^ 1);
    bf16x8 af[2], bfr[4];
#pragma unroll
    for (int mi = 0; mi < 2; ++mi)
      af[mi] = *reinterpret_cast<const bf16x8*>(&sA[cur][(wm * 32 + mi * 16 + lr) * 32 + lg * 8]);
#pragma unroll
    for (int ni = 0; ni < 4; ++ni)
      bfr[ni] = *reinterpret_cast<const bf16x8*>(&sB[cur][(wn * 64 + ni * 16 + lr) * 32 + lg * 8]);
#pragma unroll
    for (int mi = 0; mi < 2; ++mi)
#pragma unroll
      for (int ni = 0; ni < 4; ++ni)
        acc[mi][ni] = __builtin_amdgcn_mfma_f32_16x16x32_bf16(af[mi], bfr[ni], acc[mi][ni], 0, 0, 0);
    __syncthreads();
    cur ^= 1;
  }

  const int colbase = n0 + wn * 64;
  if (colbase >= 1600) return;
  if (colbase < 960) {
#pragma unroll
    for (int mi = 0; mi < 2; ++mi) {
      const int row = m0 + wm * 32 + mi * 16 + lg * 4;
#pragma unroll
      for (int ni = 0; ni < 2; ++ni) {
        const int d = ni * 16 + lr;
#pragma unroll
        for (int r = 0; r < 4; ++r) {
          const int pos = row + r;
          float2 cs = cstab[pos * 32 + d];
          float x1 = acc[mi][ni][r], x2 = acc[mi][ni + 2][r];
          qr[(size_t)pos * 960 + colbase + d] =
              __float2bfloat16((x1 * cs.x - x2 * cs.y) * QSCL);
          qr[(size_t)pos * 960 + colbase + d + 32] =
              __float2bfloat16((x2 * cs.x + x1 * cs.y) * QSCL);
        }
      }
    }
  } else if (colbase < 1280) {
    const int cb = colbase - 960;
    const int kvh = cb >> 6;
#pragma unroll
    for (int mi = 0; mi < 2; ++mi) {
      const int row = m0 + wm * 32 + mi * 16 + lg * 4;
#pragma unroll
      for (int ni = 0; ni < 2; ++ni) {
        const int d = ni * 16 + lr;
#pragma unroll
        for (int r = 0; r < 4; ++r) {
          const int pos = row + r;
          float2 cs = cstab[pos * 32 + d];
          float v1 = acc[mi][ni][r] * cs.x - acc[mi][ni + 2][r] * cs.y;
          float v2 = acc[mi][ni + 2][r] * cs.x + acc[mi][ni][r] * cs.y;
          const size_t blk = ((size_t)(pos >> 5) * 5 + kvh) * 2048;
          const int dl1 = d, dl2 = d + 32;
          kr2[blk + (size_t)(((dl1 >> 4) << 6) + (((dl1 >> 3) & 1) << 5) + (pos & 31)) * 8 + (dl1 & 7)] =
              __float2bfloat16(v1);
          kr2[blk + (size_t)(((dl2 >> 4) << 6) + (((dl2 >> 3) & 1) << 5) + (pos & 31)) * 8 + (dl2 & 7)] =
              __float2bfloat16(v2);
        }
      }
    }
  } else {
#pragma unroll
    for (int mi = 0; mi < 2; ++mi) {
      const int row = m0 + wm * 32 + mi * 16 + lg * 4;
#pragma unroll
      for (int ni = 0; ni < 4; ++ni) {
        const int vc = colbase - 1280 + ni * 16 + lr;
        ushort4 pk;
        pk.x = f2bfu(acc[mi][ni][0]);
        pk.y = f2bfu(acc[mi][ni][1]);
        pk.z = f2bfu(acc[mi][ni][2]);
        pk.w = f2bfu(acc[mi][ni][3]);
        const int db = (vc >> 5) & 1, dq = vc & 31;
        const int pb = (row >> 4) & 1, h2 = (row >> 3) & 1;
        const size_t blk = ((size_t)(row >> 5) * 5 + (vc >> 6)) * 2048;
        *reinterpret_cast<ushort4*>(
            &vTb2[blk + (size_t)(((db * 2 + pb) << 6) + (h2 << 5) + dq) * 8 + (row & 7)]) = pk;
      }
    }
  }
}

// ---------------- persistent-wave flash attention (1 item / block) ----------
__launch_bounds__(64)
__global__ void attn_part8(const bf16* __restrict__ q, const bf16* __restrict__ kr2,
                           const bf16* __restrict__ vTb2, const int* __restrict__ items,
                           bf16* __restrict__ pacc, float* __restrict__ pml) {
  const int lane = threadIdx.x & 63;
  const int ql = lane & 31, hi = lane >> 5;
  const int kvoff = 4 * hi;

  for (int it = blockIdx.x; it < 4320; it += 4320) {
    const int v = items[it];
    const int qt = v & 255, head = (v >> 8) & 255, c = v >> 16;
    const int q0 = qt * 32;
    const int kvh = head / 3;
    const int t0 = c * 8, t1 = min(t0 + 8, qt + 1);
    const int qrow = q0 + ql;

    bf16x8 qf0 = *reinterpret_cast<const bf16x8*>(&q[(size_t)(q0 + ql) * 960 + head * 64 + hi * 8]);
    bf16x8 qf1 = *reinterpret_cast<const bf16x8*>(&q[(size_t)(q0 + ql) * 960 + head * 64 + 16 + hi * 8]);
    bf16x8 qf2 = *reinterpret_cast<const bf16x8*>(&q[(size_t)(q0 + ql) * 960 + head * 64 + 32 + hi * 8]);
    bf16x8 qf3 = *reinterpret_cast<const bf16x8*>(&q[(size_t)(q0 + ql) * 960 + head * 64 + 48 + hi * 8]);

    f32x16 acc0 = {}, acc1 = {};
    float mrun = -1e30f, lrun = 0.f;
    const bf16* kp = kr2 + ((size_t)t0 * 5 + kvh) * 2048 + (hi * 32 + ql) * 8;
    const bf16* vp = vTb2 + ((size_t)t0 * 5 + kvh) * 2048 + (hi * 32 + ql) * 8;

    for (int kb = t0; kb < t1; ++kb) {
      bf16x8 kc0 = *reinterpret_cast<const bf16x8*>(kp);
      bf16x8 kc1 = *reinterpret_cast<const bf16x8*>(kp + 512);
      bf16x8 kc2 = *reinterpret_cast<const bf16x8*>(kp + 1024);
      bf16x8 kc3 = *reinterpret_cast<const bf16x8*>(kp + 1536);
      bf16x8 vc0 = *reinterpret_cast<const bf16x8*>(vp);
      bf16x8 vc1 = *reinterpret_cast<const bf16x8*>(vp + 512);
      bf16x8 vc2 = *reinterpret_cast<const bf16x8*>(vp + 1024);
      bf16x8 vc3 = *reinterpret_cast<const bf16x8*>(vp + 1536);

      __builtin_amdgcn_s_setprio(1);
      f32x16 sa = {}, sb = {};
      sa = __builtin_amdgcn_mfma_f32_32x32x16_bf16(kc0, qf0, sa, 0, 0, 0);
      sb = __builtin_amdgcn_mfma_f32_32x32x16_bf16(kc1, qf1, sb, 0, 0, 0);
      sa = __builtin_amdgcn_mfma_f32_32x32x16_bf16(kc2, qf2, sa, 0, 0, 0);
      sb = __builtin_amdgcn_mfma_f32_32x32x16_bf16(kc3, qf3, sb, 0, 0, 0);
      __builtin_amdgcn_s_setprio(0);

      if (kb == qt) {
        const int kvb = kb * 32;
#pragma unroll
        for (int r = 0; r < 16; ++r) {
          const int kv = kvb + kvoff + (r & 3) + 8 * (r >> 2);
          float sv = sa[r] + sb[r];
          sa[r] = (kv > qrow) ? -1e30f : sv;
        }
      } else {
#pragma unroll
        for (int r = 0; r < 16; ++r) sa[r] += sb[r];
      }

      float m0_ = fmaxf(fmaxf(sa[0], sa[1]), fmaxf(sa[2], sa[3]));
      float m1_ = fmaxf(fmaxf(sa[4], sa[5]), fmaxf(sa[6], sa[7]));
      float m2_ = fmaxf(fmaxf(sa[8], sa[9]), fmaxf(sa[10], sa[11]));
      float m3_ = fmaxf(fmaxf(sa[12], sa[13]), fmaxf(sa[14], sa[15]));
      float tm = fmaxf(fmaxf(m0_, m1_), fmaxf(m2_, m3_));
      tm = fmaxf(tm, __shfl_xor(tm, 32));
      if (__any(tm > mrun + 11.5f)) {
        const float mn = fmaxf(mrun, tm);
        const float ef = exp2f(mrun - mn);
        mrun = mn;
#pragma unroll
        for (int r = 0; r < 16; ++r) { acc0[r] *= ef; acc1[r] *= ef; }
        lrun *= ef;
      }
#pragma unroll
      for (int r = 0; r < 16; ++r) sa[r] = exp2f(sa[r] - mrun);
      float t0_ = (sa[0] + sa[1]) + (sa[2] + sa[3]);
      float t1_ = (sa[4] + sa[5]) + (sa[6] + sa[7]);
      float t2_ = (sa[8] + sa[9]) + (sa[10] + sa[11]);
      float t3_ = (sa[12] + sa[13]) + (sa[14] + sa[15]);
      float ts = (t0_ + t1_) + (t2_ + t3_);
      ts += __shfl_xor(ts, 32);
      lrun += ts;

      unsigned int a0 = cvtpk(sa[0], sa[1]), a1 = cvtpk(sa[2], sa[3]);
      unsigned int a2 = cvtpk(sa[4], sa[5]), a3 = cvtpk(sa[6], sa[7]);
      unsigned int b0 = cvtpk(sa[8], sa[9]), b1 = cvtpk(sa[10], sa[11]);
      unsigned int b2 = cvtpk(sa[12], sa[13]), b3 = cvtpk(sa[14], sa[15]);
      asm volatile("v_permlane32_swap_b32 %0, %1" : "+v"(a0), "+v"(a2));
      asm volatile("v_permlane32_swap_b32 %0, %1" : "+v"(a1), "+v"(a3));
      asm volatile("v_permlane32_swap_b32 %0, %1" : "+v"(b0), "+v"(b2));
      asm volatile("v_permlane32_swap_b32 %0, %1" : "+v"(b1), "+v"(b3));
      union { unsigned int u[4]; bf16x8 v; } f0, f1;
      f0.u[0] = a0; f0.u[1] = a1; f0.u[2] = a2; f0.u[3] = a3;
      f1.u[0] = b0; f1.u[1] = b1; f1.u[2] = b2; f1.u[3] = b3;

      __builtin_amdgcn_s_setprio(1);
      acc0 = __builtin_amdgcn_mfma_f32_32x32x16_bf16(vc0, f0.v, acc0, 0, 0, 0);
      acc1 = __builtin_amdgcn_mfma_f32_32x32x16_bf16(vc2, f0.v, acc1, 0, 0, 0);
      acc0 = __builtin_amdgcn_mfma_f32_32x32x16_bf16(vc1, f1.v, acc0, 0, 0, 0);
      acc1 = __builtin_amdgcn_mfma_f32_32x32x16_bf16(vc3, f1.v, acc1, 0, 0, 0);
      __builtin_amdgcn_s_setprio(0);

      kp += 5 * 2048;
      vp += 5 * 2048;
    }

    const size_t base = (size_t)it * 2048;
#pragma unroll
    for (int r = 0; r < 16; ++r) {
      const int row = (r & 3) + 8 * (r >> 2) + kvoff;
      pacc[base + (size_t)row * 32 + ql] = __float2bfloat16(acc0[r]);
      pacc[base + (size_t)(row + 32) * 32 + ql] = __float2bfloat16(acc1[r]);
    }
    const size_t mb = (size_t)it * 64;
    if (!hi) {
      pml[mb + ql * 2] = mrun;
      pml[mb + ql * 2 + 1] = lrun;
    }
  }
}

// ---------------- attention merge (exp2 domain, triangular slots) -----------
__launch_bounds__(256)
__global__ void attn_merge4(const bf16* __restrict__ pacc, const float* __restrict__ pml,
                            bf16* __restrict__ ctx) {
  const int qt = blockIdx.x, head = blockIdx.y;
  const int a = qt >> 3, bq = qt & 7;
  const int psum = qt + 8 * (a * (a - 1) / 2) + a * bq;
  const int slot0 = head * 288 + psum;
  const int nch = (qt >> 3) + 1;
  const size_t base = (size_t)slot0 * 2048;
  const size_t mb = (size_t)slot0 * 64;
  __shared__ float smem[32][65];
  for (int i = threadIdx.x; i < 2048; i += 256) {
    const int qi = i & 31, d = i >> 5;
    float m = -1e30f;
    for (int c = 0; c < nch; ++c) m = fmaxf(m, pml[mb + c * 64 + qi * 2]);
    float lsum = 0.f, o = 0.f;
    for (int c = 0; c < nch; ++c) {
      float e = exp2f(pml[mb + c * 64 + qi * 2] - m);
      lsum += pml[mb + c * 64 + qi * 2 + 1] * e;
      o += __bfloat162float(pacc[base + c * 2048 + d * 32 + qi]) * e;
    }
    smem[qi][d] = o / lsum;
  }
  __syncthreads();
  for (int i = threadIdx.x; i < 2048; i += 256) {
    const int qi = i >> 6, d = i & 63;
    ctx[(size_t)(qt * 32 + qi) * 960 + head * 64 + d] = __float2bfloat16(smem[qi][d]);
  }
}

// ---------------- launch ----------------------------------------------------
extern "C" void kernel_launch(void* const* d_in, const int* in_sizes, int n_in,
                              void* d_out, int out_size, void* d_ws, size_t ws_size,
                              hipStream_t stream) {
  const float* x  = (const float*)d_in[0];
  const float* wq = (const float*)d_in[1];
  const float* wk = (const float*)d_in[2];
  const float* wv = (const float*)d_in[3];
  const float* wo = (const float*)d_in[4];
  const float* wg = (const float*)d_in[5];
  const float* wu = (const float*)d_in[6];
  const float* wd = (const float*)d_in[7];
  const float* g1 = (const float*)d_in[8];
  const float* g2 = (const float*)d_in[9];
  float* out = (float*)d_out;

  char* ws = (char*)d_ws;
  bf16*   wT    = (bf16*)ws;                       // 0 .. 20,111,360
  bf16*   pacc  = (bf16*)(ws + 20111360);          // 17,694,720 (attn partials)
  __half* Ppart = (__half*)(ws + 20111360);        // 15,728,640 (wo partials, after merge)
  float*  pml   = (float*)(ws + 37806080);         // 1,105,920 (ends 38,912,000)
  bf16*   qr    = (bf16*)(ws + 38912000);          // 3,932,160
  bf16*   kr2   = (bf16*)(ws + 42844160);          // 1,310,720
  bf16*   vTb2  = (bf16*)(ws + 44154880);          // 1,310,720
  bf16*   ctx   = (bf16*)(ws + 45465600);          // 3,932,160 (ends 49,397,760)
  bf16*   actb  = (bf16*)(ws + 38912000);          // 10,485,760 (overlays qr..ctx, post-wo)
  bf16*   nbF   = (bf16*)(ws + 49397760);          // 3,932,160
  bf16*   nbK   = (bf16*)(ws + 53329920);          // 3,932,160
  float2* cst   = (float2*)(ws + 57262080);        // 524,288
  int*    items = (int*)(ws + 57786368);           // 17,280 (total ~57.8 MB)

  bf16* wqkvT = wT;            // 1600 x 960 (q|k|v rows)
  bf16* wkT  = wT + 921600;    // 640 x 960 (k|v rows) for kv GEMM
  bf16* woT  = wT + 1536000;   // 1024 x 960 (rows 960+ pad)
  bf16* wguT = wT + 2519040;   // 5120 x 960 interleaved [gate16|up16]
  bf16* wdT  = wT + 7434240;   // 1024 x 2560 (rows 960+ pad)

  dim3 blk(256);
  prep2_k<<<4708, blk, 0, stream>>>(wq, wk, wv, wo, wg, wu, wd,
                                    wqkvT, woT, wguT, wdT, cst, items, x, g1, nbF);
  gemm_qkv<<<dim3(13, 32), blk, 0, stream>>>(nbF, wqkvT, cst, qr, kr2, vTb2);
  attn_part8<<<4320, dim3(64), 0, stream>>>(qr, kr2, vTb2, items, pacc, pml);
  attn_merge4<<<dim3(64, 15), blk, 0, stream>>>(pacc, pml, ctx);
  gemm_sk<0><<<dim3(8, 16, 4), blk, 0, stream>>>(ctx, woT, Ppart, nullptr, 960, 960, 30, 8);
  rmsfuse2_k<<<2560, blk, 0, stream>>>(Ppart, x, g1, g2, out, nbF, nbK);
  gemm_ffn<<<dim3(40, 16), blk, 0, stream>>>(nbF, wguT, actb);
  gemm_sk<2><<<dim3(5, 16, 4), blk, 0, stream>>>(nbK, wkT, nullptr, out + 1966080, 640, 960, 30, 8);
  gemm_sk<1><<<dim3(8, 16, 4), blk, 0, stream>>>(actb, wdT, nullptr, out, 960, 2560, 80, 20);
}

// Round 15
// 212.646 us; speedup vs baseline: 1.0075x; 1.0075x over previous
//
#include <hip/hip_runtime.h>
#include <hip/hip_bf16.h>
#include <hip/hip_fp16.h>

// TextEncoderBlock R15: kv GEMM merged into ffn launch as tail-fill (ffn keeps
// NATURAL mapping — R12's regression was the swizzle, not the merge; kv blocks
// appended with their proven swizzle + atomicAdd). Rest identical to R14.
// B=1 L=2048 EMBD=960 FFN=2560 QH=15 KVH=5 HD=64

typedef __hip_bfloat16 bf16;
typedef __attribute__((ext_vector_type(8))) short bf16x8;
typedef __attribute__((ext_vector_type(4))) float f32x4;
typedef __attribute__((ext_vector_type(16))) float f32x16;

#define EPS 1.1920929e-07f
#define QSCL 0.1803368801111f  /* 0.125 * log2(e) */

__device__ __forceinline__ void gload_lds16(const bf16* g, bf16* l) {
  __builtin_amdgcn_global_load_lds(
      (const __attribute__((address_space(1))) unsigned int*)g,
      (__attribute__((address_space(3))) unsigned int*)l, 16, 0, 0);
}

__device__ __forceinline__ unsigned short f2bfu(float f) {
  __hip_bfloat16 b = __float2bfloat16(f);
  return *reinterpret_cast<unsigned short*>(&b);
}
__device__ __forceinline__ float bfu2f(unsigned short u) {
  return __uint_as_float(((unsigned int)u) << 16);
}
__device__ __forceinline__ float hu2f(unsigned short u) {
  __half_raw r; r.x = u;
  return __half2float((__half)r);
}
__device__ __forceinline__ unsigned int cvtpk(float lo, float hi_) {
  unsigned int r;
  asm("v_cvt_pk_bf16_f32 %0, %1, %2" : "=v"(r) : "v"(lo), "v"(hi_));
  return r;
}

// ---------------- shared 128x128 GEMM core (BK=32, dbuf, ptr-increment) -----
__device__ __forceinline__ void gemm_core128(const bf16* __restrict__ A,
    const bf16* __restrict__ BT, int K, int ks0, int ks1, int m0, int n0,
    bf16 (&sA)[2][4096], bf16 (&sB)[2][4096], f32x4 (&acc)[4][4]) {
  const int t = threadIdx.x, w = t >> 6, lane = t & 63;
  const int lg = lane >> 4, lr = lane & 15;
  const int wm = w >> 1, wn = w & 1;
  const int c0 = w * 128 + lane;
  const int c1 = c0 + 64;
  const bf16* pA0 = A + (size_t)(m0 + (c0 >> 2)) * K + ks0 * 32 + (c0 & 3) * 8;
  const bf16* pA1 = A + (size_t)(m0 + (c1 >> 2)) * K + ks0 * 32 + (c1 & 3) * 8;
  const bf16* pB0 = BT + (size_t)(n0 + (c0 >> 2)) * K + ks0 * 32 + (c0 & 3) * 8;
  const bf16* pB1 = BT + (size_t)(n0 + (c1 >> 2)) * K + ks0 * 32 + (c1 & 3) * 8;
  bf16* const dA0[2] = {&sA[0][c0 * 8], &sA[1][c0 * 8]};
  bf16* const dA1[2] = {&sA[0][c1 * 8], &sA[1][c1 * 8]};
  bf16* const dB0[2] = {&sB[0][c0 * 8], &sB[1][c0 * 8]};
  bf16* const dB1[2] = {&sB[0][c1 * 8], &sB[1][c1 * 8]};
  auto stage = [&](int buf) {
    gload_lds16(pA0, dA0[buf]);
    gload_lds16(pA1, dA1[buf]);
    gload_lds16(pB0, dB0[buf]);
    gload_lds16(pB1, dB1[buf]);
    pA0 += 32; pA1 += 32; pB0 += 32; pB1 += 32;
  };
  stage(0);
  __syncthreads();
  int cur = 0;
  for (int ks = ks0; ks < ks1; ++ks) {
    if (ks + 1 < ks1) stage(cur ^ 1);
    bf16x8 af[4], bfr[4];
#pragma unroll
    for (int mi = 0; mi < 4; ++mi)
      af[mi] = *reinterpret_cast<const bf16x8*>(&sA[cur][(wm * 64 + mi * 16 + lr) * 32 + lg * 8]);
#pragma unroll
    for (int ni = 0; ni < 4; ++ni)
      bfr[ni] = *reinterpret_cast<const bf16x8*>(&sB[cur][(wn * 64 + ni * 16 + lr) * 32 + lg * 8]);
#pragma unroll
    for (int mi = 0; mi < 4; ++mi)
#pragma unroll
      for (int ni = 0; ni < 4; ++ni)
        acc[mi][ni] = __builtin_amdgcn_mfma_f32_16x16x32_bf16(af[mi], bfr[ni], acc[mi][ni], 0, 0, 0);
    __syncthreads();
    cur ^= 1;
  }
}

// ---------------- fused prep: transposes + rope + items + first rmsnorm -----
__device__ void do_transpose(float (*tile)[65], const float* __restrict__ W,
                             bf16* __restrict__ WT, int K, int N, int bx, int by,
                             int map) {
  const int k0 = by * 64, n0 = bx * 64;
  const int tx = threadIdx.x & 63, ty = threadIdx.x >> 6;
#pragma unroll
  for (int i = 0; i < 16; ++i) {
    int r = ty + i * 4;
    tile[r][tx] = W[(size_t)(k0 + r) * N + n0 + tx];
  }
  __syncthreads();
#pragma unroll
  for (int i = 0; i < 16; ++i) {
    int r = ty + i * 4;
    int v = n0 + r;
    int row = (map == 0) ? v : ((v >> 4) << 5) + (v & 15) + (map == 2 ? 16 : 0);
    WT[(size_t)row * K + k0 + tx] = __float2bfloat16(tile[tx][r]);
  }
}

__launch_bounds__(256)
__global__ void prep2_k(const float* __restrict__ wq, const float* __restrict__ wk,
                        const float* __restrict__ wv, const float* __restrict__ wo,
                        const float* __restrict__ wg, const float* __restrict__ wu,
                        const float* __restrict__ wd, bf16* __restrict__ wqkvT,
                        bf16* __restrict__ woT, bf16* __restrict__ wguT,
                        bf16* __restrict__ wdT, float2* __restrict__ cstab,
                        int* __restrict__ items, const float* __restrict__ x,
                        const float* __restrict__ g1, bf16* __restrict__ nb) {
  __shared__ float tile[64][65];
  int b = blockIdx.x;
  if (b < 225) {
    do_transpose(tile, wq, wqkvT, 960, 960, b % 15, b / 15, 0);
  } else if (b < 300) {
    b -= 225;
    do_transpose(tile, wk, wqkvT + 921600, 960, 320, b % 5, b / 5, 0);
  } else if (b < 375) {
    b -= 300;
    do_transpose(tile, wv, wqkvT + 1228800, 960, 320, b % 5, b / 5, 0);
  } else if (b < 600) {
    b -= 375;
    do_transpose(tile, wo, woT, 960, 960, b % 15, b / 15, 0);
  } else if (b < 1200) {
    b -= 600;
    do_transpose(tile, wg, wguT, 960, 2560, b % 40, b / 40, 1);
  } else if (b < 1800) {
    b -= 1200;
    do_transpose(tile, wu, wguT, 960, 2560, b % 40, b / 40, 2);
  } else if (b < 2400) {
    b -= 1800;
    do_transpose(tile, wd, wdT, 2560, 960, b % 15, b / 15, 0);
  } else if (b < 2656) {
    const int idx = (b - 2400) * 256 + threadIdx.x;
    const int pos = idx >> 5, d = idx & 31;
    float inv = powf(10000.f, -(float)d * (1.f / 32.f));
    float rad = (float)pos * inv;
    cstab[idx] = make_float2(cosf(rad), sinf(rad));
  } else if (b < 2660) {
    const int idx = (b - 2656) * 256 + threadIdx.x;
    if (idx < 960) {
      const int head = idx >> 6, qt = idx & 63;
      const int a = qt >> 3, bq = qt & 7;
      const int psum = qt + 8 * (a * (a - 1) / 2) + a * bq;
      const int base = head * 288 + psum;
      const int nch = (qt >> 3) + 1;
      for (int c = 0; c < nch; ++c)
        items[base + c] = qt | (head << 8) | (c << 16);
    }
  } else {
    const int row = b - 2660;
    const float* xr = x + (size_t)row * 960;
    const int t = threadIdx.x;
    float4 v = {0.f, 0.f, 0.f, 0.f};
    float ss = 0.f;
    if (t < 240) {
      v = *reinterpret_cast<const float4*>(&xr[t * 4]);
      ss = v.x * v.x + v.y * v.y + v.z * v.z + v.w * v.w;
    }
#pragma unroll
    for (int off = 32; off; off >>= 1) ss += __shfl_down(ss, off);
    __shared__ float red[4];
    __shared__ float s_scale;
    if ((t & 63) == 0) red[t >> 6] = ss;
    __syncthreads();
    if (t == 0) {
      float tot = red[0] + red[1] + red[2] + red[3];
      s_scale = rsqrtf(tot * (1.f / 960.f) + EPS);
    }
    __syncthreads();
    if (t < 240) {
      const float sc = s_scale;
      const float4 gv = *reinterpret_cast<const float4*>(&g1[t * 4]);
      ushort4 o;
      o.x = f2bfu(v.x * sc * gv.x);
      o.y = f2bfu(v.y * sc * gv.y);
      o.z = f2bfu(v.z * sc * gv.z);
      o.w = f2bfu(v.w * sc * gv.w);
      *reinterpret_cast<ushort4*>(&nb[(size_t)row * 960 + t * 4]) = o;
    }
  }
}

// ---------------- rmsfuse2: out=sum(P)+x (residual2); dual norm; kv zero ----
__launch_bounds__(256)
__global__ void rmsfuse2_k(const __half* __restrict__ P, const float* __restrict__ x,
                           const float* __restrict__ g1, const float* __restrict__ g2,
                           float* __restrict__ outp, bf16* __restrict__ nbF,
                           bf16* __restrict__ nbK) {
  if (blockIdx.x >= 2048) {
    const int zb = blockIdx.x - 2048;
    for (int i = zb * 256 + threadIdx.x; i < 327680; i += 131072) {
      float4 z = {0.f, 0.f, 0.f, 0.f};
      *reinterpret_cast<float4*>(&outp[1966080 + (size_t)i * 4]) = z;
    }
    return;
  }
  const int row = blockIdx.x;
  const int t = threadIdx.x;
  float4 v = {0.f, 0.f, 0.f, 0.f};
  float ss = 0.f;
  if (t < 240) {
    const size_t e = (size_t)row * 960 + t * 4;
    v = *reinterpret_cast<const float4*>(&x[e]);
#pragma unroll
    for (int s = 0; s < 4; ++s) {
      ushort4 pa = *reinterpret_cast<const ushort4*>(&P[(size_t)s * 1966080 + e]);
      v.x += hu2f(pa.x); v.y += hu2f(pa.y); v.z += hu2f(pa.z); v.w += hu2f(pa.w);
    }
    ss = v.x * v.x + v.y * v.y + v.z * v.z + v.w * v.w;
  }
#pragma unroll
  for (int off = 32; off; off >>= 1) ss += __shfl_down(ss, off);
  __shared__ float red[4];
  __shared__ float s_scale;
  if ((t & 63) == 0) red[t >> 6] = ss;
  __syncthreads();
  if (t == 0) {
    float tot = red[0] + red[1] + red[2] + red[3];
    s_scale = rsqrtf(tot * (1.f / 960.f) + EPS);
  }
  __syncthreads();
  if (t < 240) {
    const size_t e = (size_t)row * 960 + t * 4;
    const float sc = s_scale;
    *reinterpret_cast<float4*>(&outp[e]) = v;
    const float4 gv2 = *reinterpret_cast<const float4*>(&g2[t * 4]);
    const float4 gv1 = *reinterpret_cast<const float4*>(&g1[t * 4]);
    ushort4 oF, oK;
    oF.x = f2bfu(v.x * sc * gv2.x); oF.y = f2bfu(v.y * sc * gv2.y);
    oF.z = f2bfu(v.z * sc * gv2.z); oF.w = f2bfu(v.w * sc * gv2.w);
    oK.x = f2bfu(v.x * sc * gv1.x); oK.y = f2bfu(v.y * sc * gv1.y);
    oK.z = f2bfu(v.z * sc * gv1.z); oK.w = f2bfu(v.w * sc * gv1.w);
    *reinterpret_cast<ushort4*>(&nbF[e]) = oF;
    *reinterpret_cast<ushort4*>(&nbK[e]) = oK;
  }
}

// ---------------- merged FFN (natural mapping) + kv split-K (tail fill) -----
// grid 960: blocks 0..639 ffn (bx=b%40, by=b/40 — identical to dim3(40,16));
// blocks 640..959 kv (proven swizzle, atomicAdd into out kv region).
__launch_bounds__(256)
__global__ void ffnkv2_k(const bf16* __restrict__ nbF, const bf16* __restrict__ wguT,
                         bf16* __restrict__ actb, const bf16* __restrict__ nbK,
                         const bf16* __restrict__ wkT, float* __restrict__ outp) {
  __shared__ __align__(16) bf16 sA[2][4096];
  __shared__ __align__(16) bf16 sB[2][4096];
  const int b = blockIdx.x;
  const int t = threadIdx.x, w = t >> 6, lane = t & 63;
  const int lg = lane >> 4, lr = lane & 15;
  const int wm = w >> 1, wn = w & 1;
  f32x4 acc[4][4] = {};

  if (b < 640) {
    // ---- ffn: natural mapping (matches R13/R14's separate launch) ----
    const int bx = b % 40, by = b / 40;
    const int m0 = by * 128, n0 = bx * 128;
    gemm_core128(nbF, wguT, 960, 0, 30, m0, n0, sA, sB, acc);
    const int colbase = n0 + wn * 64;
#pragma unroll
    for (int mi = 0; mi < 4; ++mi) {
      const int row = m0 + wm * 64 + mi * 16 + lg * 4;
#pragma unroll
      for (int p = 0; p < 2; ++p) {
        const int oc = ((colbase >> 5) + p) * 16 + lr;
#pragma unroll
        for (int r = 0; r < 4; ++r) {
          float gf = acc[mi][2 * p][r], uf = acc[mi][2 * p + 1][r];
          float s = gf / (1.f + __expf(-gf));
          actb[(size_t)(row + r) * 2560 + oc] = __float2bfloat16(s * uf);
        }
      }
    }
  } else {
    // ---- kv: split-K x4 swizzled, atomicAdd into out kv region ----
    const int lb = b - 640;
    const int sid = (lb & 7) * 40 + (lb >> 3);
    const int bx = sid % 5, by = (sid / 5) % 16, bz = sid / 80;
    const int m0 = by * 128, n0 = bx * 128;
    const int ks0 = bz * 8, ks1 = min(ks0 + 8, 30);
    gemm_core128(nbK, wkT, 960, ks0, ks1, m0, n0, sA, sB, acc);
#pragma unroll
    for (int mi = 0; mi < 4; ++mi) {
      const int row = m0 + wm * 64 + mi * 16 + lg * 4;
#pragma unroll
      for (int ni = 0; ni < 4; ++ni) {
        const int col = n0 + wn * 64 + ni * 16 + lr;
#pragma unroll
        for (int r = 0; r < 4; ++r) {
          const int rr = row + r;
          float* dst = (col < 320) ? outp + 1966080 + (size_t)rr * 320 + col
                                   : outp + 2621440 + (size_t)rr * 320 + (col - 320);
          atomicAdd(dst, acc[mi][ni][r]);
        }
      }
    }
  }
}

// ---------------- split-K GEMM: MODE 0 fp16 partials, MODE 1 atomic out -----
template <int MODE>
__launch_bounds__(256)
__global__ void gemm_sk(const bf16* __restrict__ A, const bf16* __restrict__ BT,
                        __half* __restrict__ P, float* __restrict__ Cf,
                        int N, int K, int nsteps, int spl) {
  __shared__ __align__(16) bf16 sA[2][4096];
  __shared__ __align__(16) bf16 sB[2][4096];
  const int nx = gridDim.x, ny = gridDim.y;
  const int total = nx * ny * gridDim.z;
  const int lid = blockIdx.x + nx * (blockIdx.y + ny * blockIdx.z);
  const int cpx = total >> 3;
  const int sid = (lid & 7) * cpx + (lid >> 3);
  const int bx = sid % nx, by = (sid / nx) % ny, bz = sid / (nx * ny);
  const int t = threadIdx.x, w = t >> 6, lane = t & 63;
  const int lg = lane >> 4, lr = lane & 15;
  const int wm = w >> 1, wn = w & 1;
  const int m0 = by * 128, n0 = bx * 128;
  const int ks0 = bz * spl, ks1 = min(ks0 + spl, nsteps);
  f32x4 acc[4][4] = {};
  gemm_core128(A, BT, K, ks0, ks1, m0, n0, sA, sB, acc);

  if (MODE == 0) {
    __half* Ps = P + (size_t)bz * 2048 * N;
#pragma unroll
    for (int mi = 0; mi < 4; ++mi) {
      const int row = m0 + wm * 64 + mi * 16 + lg * 4;
#pragma unroll
      for (int ni = 0; ni < 4; ++ni) {
        const int col = n0 + wn * 64 + ni * 16 + lr;
        if (col < N) {
#pragma unroll
          for (int r = 0; r < 4; ++r)
            Ps[(size_t)(row + r) * N + col] = __float2half(acc[mi][ni][r]);
        }
      }
    }
  } else {
#pragma unroll
    for (int mi = 0; mi < 4; ++mi) {
      const int row = m0 + wm * 64 + mi * 16 + lg * 4;
#pragma unroll
      for (int ni = 0; ni < 4; ++ni) {
        const int col = n0 + wn * 64 + ni * 16 + lr;
        if (col < N) {
#pragma unroll
          for (int r = 0; r < 4; ++r)
            atomicAdd(&Cf[(size_t)(row + r) * N + col], acc[mi][ni][r]);
        }
      }
    }
  }
}

// ---------------- QKV GEMM 64x128, fused RoPE + fragment-order K/V ----------
__launch_bounds__(256)
__global__ void gemm_qkv(const bf16* __restrict__ A, const bf16* __restrict__ BT,
                         const float2* __restrict__ cstab, bf16* __restrict__ qr,
                         bf16* __restrict__ kr2, bf16* __restrict__ vTb2) {
  const int N = 1600, K = 960;
  __shared__ __align__(16) bf16 sA[2][64 * 32];
  __shared__ __align__(16) bf16 sB[2][128 * 32];
  const int t = threadIdx.x, w = t >> 6, lane = t & 63;
  const int lg = lane >> 4, lr = lane & 15;
  const int wm = w >> 1, wn = w & 1;
  const int m0 = blockIdx.y * 64, n0 = blockIdx.x * 128;
  f32x4 acc[2][4] = {};
  const int nsteps = K / 32;

  const int cA = t, cB0 = t, cB1 = t + 256;
  const bf16* pA = A + (size_t)(m0 + (cA >> 2)) * K + (cA & 3) * 8;
  int brow0 = n0 + (cB0 >> 2); if (brow0 >= N) brow0 = N - 1;
  int brow1 = n0 + (cB1 >> 2); if (brow1 >= N) brow1 = N - 1;
  const bf16* pB0 = BT + (size_t)brow0 * K + (cB0 & 3) * 8;
  const bf16* pB1 = BT + (size_t)brow1 * K + (cB1 & 3) * 8;
  auto stage = [&](int buf) {
    gload_lds16(pA, &sA[buf][cA * 8]);
    gload_lds16(pB0, &sB[buf][cB0 * 8]);
    gload_lds16(pB1, &sB[buf][cB1 * 8]);
    pA += 32; pB0 += 32; pB1 += 32;
  };

  stage(0);
  __syncthreads();
  int cur = 0;
  for (int ks = 0; ks < nsteps; ++ks) {
    if (ks + 1 < nsteps) stage(cur ^ 1);
    bf16x8 af[2], bfr[4];
#pragma unroll
    for (int mi = 0; mi < 2; ++mi)
      af[mi] = *reinterpret_cast<const bf16x8*>(&sA[cur][(wm * 32 + mi * 16 + lr) * 32 + lg * 8]);
#pragma unroll
    for (int ni = 0; ni < 4; ++ni)
      bfr[ni] = *reinterpret_cast<const bf16x8*>(&sB[cur][(wn * 64 + ni * 16 + lr) * 32 + lg * 8]);
#pragma unroll
    for (int mi = 0; mi < 2; ++mi)
#pragma unroll
      for (int ni = 0; ni < 4; ++ni)
        acc[mi][ni] = __builtin_amdgcn_mfma_f32_16x16x32_bf16(af[mi], bfr[ni], acc[mi][ni], 0, 0, 0);
    __syncthreads();
    cur ^= 1;
  }

  const int colbase = n0 + wn * 64;
  if (colbase >= 1600) return;
  if (colbase < 960) {
#pragma unroll
    for (int mi = 0; mi < 2; ++mi) {
      const int row = m0 + wm * 32 + mi * 16 + lg * 4;
#pragma unroll
      for (int ni = 0; ni < 2; ++ni) {
        const int d = ni * 16 + lr;
#pragma unroll
        for (int r = 0; r < 4; ++r) {
          const int pos = row + r;
          float2 cs = cstab[pos * 32 + d];
          float x1 = acc[mi][ni][r], x2 = acc[mi][ni + 2][r];
          qr[(size_t)pos * 960 + colbase + d] =
              __float2bfloat16((x1 * cs.x - x2 * cs.y) * QSCL);
          qr[(size_t)pos * 960 + colbase + d + 32] =
              __float2bfloat16((x2 * cs.x + x1 * cs.y) * QSCL);
        }
      }
    }
  } else if (colbase < 1280) {
    const int cb = colbase - 960;
    const int kvh = cb >> 6;
#pragma unroll
    for (int mi = 0; mi < 2; ++mi) {
      const int row = m0 + wm * 32 + mi * 16 + lg * 4;
#pragma unroll
      for (int ni = 0; ni < 2; ++ni) {
        const int d = ni * 16 + lr;
#pragma unroll
        for (int r = 0; r < 4; ++r) {
          const int pos = row + r;
          float2 cs = cstab[pos * 32 + d];
          float v1 = acc[mi][ni][r] * cs.x - acc[mi][ni + 2][r] * cs.y;
          float v2 = acc[mi][ni + 2][r] * cs.x + acc[mi][ni][r] * cs.y;
          const size_t blk = ((size_t)(pos >> 5) * 5 + kvh) * 2048;
          const int dl1 = d, dl2 = d + 32;
          kr2[blk + (size_t)(((dl1 >> 4) << 6) + (((dl1 >> 3) & 1) << 5) + (pos & 31)) * 8 + (dl1 & 7)] =
              __float2bfloat16(v1);
          kr2[blk + (size_t)(((dl2 >> 4) << 6) + (((dl2 >> 3) & 1) << 5) + (pos & 31)) * 8 + (dl2 & 7)] =
              __float2bfloat16(v2);
        }
      }
    }
  } else {
#pragma unroll
    for (int mi = 0; mi < 2; ++mi) {
      const int row = m0 + wm * 32 + mi * 16 + lg * 4;
#pragma unroll
      for (int ni = 0; ni < 4; ++ni) {
        const int vc = colbase - 1280 + ni * 16 + lr;
        ushort4 pk;
        pk.x = f2bfu(acc[mi][ni][0]);
        pk.y = f2bfu(acc[mi][ni][1]);
        pk.z = f2bfu(acc[mi][ni][2]);
        pk.w = f2bfu(acc[mi][ni][3]);
        const int db = (vc >> 5) & 1, dq = vc & 31;
        const int pb = (row >> 4) & 1, h2 = (row >> 3) & 1;
        const size_t blk = ((size_t)(row >> 5) * 5 + (vc >> 6)) * 2048;
        *reinterpret_cast<ushort4*>(
            &vTb2[blk + (size_t)(((db * 2 + pb) << 6) + (h2 << 5) + dq) * 8 + (row & 7)]) = pk;
      }
    }
  }
}

// ---------------- persistent-wave flash attention (1 item / block) ----------
__launch_bounds__(64)
__global__ void attn_part8(const bf16* __restrict__ q, const bf16* __restrict__ kr2,
                           const bf16* __restrict__ vTb2, const int* __restrict__ items,
                           bf16* __restrict__ pacc, float* __restrict__ pml) {
  const int lane = threadIdx.x & 63;
  const int ql = lane & 31, hi = lane >> 5;
  const int kvoff = 4 * hi;

  {
    const int it = blockIdx.x;
    const int v = items[it];
    const int qt = v & 255, head = (v >> 8) & 255, c = v >> 16;
    const int q0 = qt * 32;
    const int kvh = head / 3;
    const int t0 = c * 8, t1 = min(t0 + 8, qt + 1);
    const int qrow = q0 + ql;

    bf16x8 qf0 = *reinterpret_cast<const bf16x8*>(&q[(size_t)(q0 + ql) * 960 + head * 64 + hi * 8]);
    bf16x8 qf1 = *reinterpret_cast<const bf16x8*>(&q[(size_t)(q0 + ql) * 960 + head * 64 + 16 + hi * 8]);
    bf16x8 qf2 = *reinterpret_cast<const bf16x8*>(&q[(size_t)(q0 + ql) * 960 + head * 64 + 32 + hi * 8]);
    bf16x8 qf3 = *reinterpret_cast<const bf16x8*>(&q[(size_t)(q0 + ql) * 960 + head * 64 + 48 + hi * 8]);

    f32x16 acc0 = {}, acc1 = {};
    float mrun = -1e30f, lrun = 0.f;
    const bf16* kp = kr2 + ((size_t)t0 * 5 + kvh) * 2048 + (hi * 32 + ql) * 8;
    const bf16* vp = vTb2 + ((size_t)t0 * 5 + kvh) * 2048 + (hi * 32 + ql) * 8;

    for (int kb = t0; kb < t1; ++kb) {
      bf16x8 kc0 = *reinterpret_cast<const bf16x8*>(kp);
      bf16x8 kc1 = *reinterpret_cast<const bf16x8*>(kp + 512);
      bf16x8 kc2 = *reinterpret_cast<const bf16x8*>(kp + 1024);
      bf16x8 kc3 = *reinterpret_cast<const bf16x8*>(kp + 1536);
      bf16x8 vc0 = *reinterpret_cast<const bf16x8*>(vp);
      bf16x8 vc1 = *reinterpret_cast<const bf16x8*>(vp + 512);
      bf16x8 vc2 = *reinterpret_cast<const bf16x8*>(vp + 1024);
      bf16x8 vc3 = *reinterpret_cast<const bf16x8*>(vp + 1536);

      __builtin_amdgcn_s_setprio(1);
      f32x16 sa = {}, sb = {};
      sa = __builtin_amdgcn_mfma_f32_32x32x16_bf16(kc0, qf0, sa, 0, 0, 0);
      sb = __builtin_amdgcn_mfma_f32_32x32x16_bf16(kc1, qf1, sb, 0, 0, 0);
      sa = __builtin_amdgcn_mfma_f32_32x32x16_bf16(kc2, qf2, sa, 0, 0, 0);
      sb = __builtin_amdgcn_mfma_f32_32x32x16_bf16(kc3, qf3, sb, 0, 0, 0);
      __builtin_amdgcn_s_setprio(0);

      if (kb == qt) {
        const int kvb = kb * 32;
#pragma unroll
        for (int r = 0; r < 16; ++r) {
          const int kv = kvb + kvoff + (r & 3) + 8 * (r >> 2);
          float sv = sa[r] + sb[r];
          sa[r] = (kv > qrow) ? -1e30f : sv;
        }
      } else {
#pragma unroll
        for (int r = 0; r < 16; ++r) sa[r] += sb[r];
      }

      float m0_ = fmaxf(fmaxf(sa[0], sa[1]), fmaxf(sa[2], sa[3]));
      float m1_ = fmaxf(fmaxf(sa[4], sa[5]), fmaxf(sa[6], sa[7]));
      float m2_ = fmaxf(fmaxf(sa[8], sa[9]), fmaxf(sa[10], sa[11]));
      float m3_ = fmaxf(fmaxf(sa[12], sa[13]), fmaxf(sa[14], sa[15]));
      float tm = fmaxf(fmaxf(m0_, m1_), fmaxf(m2_, m3_));
      tm = fmaxf(tm, __shfl_xor(tm, 32));
      if (__any(tm > mrun + 11.5f)) {
        const float mn = fmaxf(mrun, tm);
        const float ef = exp2f(mrun - mn);
        mrun = mn;
#pragma unroll
        for (int r = 0; r < 16; ++r) { acc0[r] *= ef; acc1[r] *= ef; }
        lrun *= ef;
      }
#pragma unroll
      for (int r = 0; r < 16; ++r) sa[r] = exp2f(sa[r] - mrun);
      float t0_ = (sa[0] + sa[1]) + (sa[2] + sa[3]);
      float t1_ = (sa[4] + sa[5]) + (sa[6] + sa[7]);
      float t2_ = (sa[8] + sa[9]) + (sa[10] + sa[11]);
      float t3_ = (sa[12] + sa[13]) + (sa[14] + sa[15]);
      float ts = (t0_ + t1_) + (t2_ + t3_);
      ts += __shfl_xor(ts, 32);
      lrun += ts;

      unsigned int a0 = cvtpk(sa[0], sa[1]), a1 = cvtpk(sa[2], sa[3]);
      unsigned int a2 = cvtpk(sa[4], sa[5]), a3 = cvtpk(sa[6], sa[7]);
      unsigned int b0 = cvtpk(sa[8], sa[9]), b1 = cvtpk(sa[10], sa[11]);
      unsigned int b2 = cvtpk(sa[12], sa[13]), b3 = cvtpk(sa[14], sa[15]);
      asm volatile("v_permlane32_swap_b32 %0, %1" : "+v"(a0), "+v"(a2));
      asm volatile("v_permlane32_swap_b32 %0, %1" : "+v"(a1), "+v"(a3));
      asm volatile("v_permlane32_swap_b32 %0, %1" : "+v"(b0), "+v"(b2));
      asm volatile("v_permlane32_swap_b32 %0, %1" : "+v"(b1), "+v"(b3));
      union { unsigned int u[4]; bf16x8 v; } f0, f1;
      f0.u[0] = a0; f0.u[1] = a1; f0.u[2] = a2; f0.u[3] = a3;
      f1.u[0] = b0; f1.u[1] = b1; f1.u[2] = b2; f1.u[3] = b3;

      __builtin_amdgcn_s_setprio(1);
      acc0 = __builtin_amdgcn_mfma_f32_32x32x16_bf16(vc0, f0.v, acc0, 0, 0, 0);
      acc1 = __builtin_amdgcn_mfma_f32_32x32x16_bf16(vc2, f0.v, acc1, 0, 0, 0);
      acc0 = __builtin_amdgcn_mfma_f32_32x32x16_bf16(vc1, f1.v, acc0, 0, 0, 0);
      acc1 = __builtin_amdgcn_mfma_f32_32x32x16_bf16(vc3, f1.v, acc1, 0, 0, 0);
      __builtin_amdgcn_s_setprio(0);

      kp += 5 * 2048;
      vp += 5 * 2048;
    }

    const size_t base = (size_t)it * 2048;
#pragma unroll
    for (int r = 0; r < 16; ++r) {
      const int row = (r & 3) + 8 * (r >> 2) + kvoff;
      pacc[base + (size_t)row * 32 + ql] = __float2bfloat16(acc0[r]);
      pacc[base + (size_t)(row + 32) * 32 + ql] = __float2bfloat16(acc1[r]);
    }
    const size_t mb = (size_t)it * 64;
    if (!hi) {
      pml[mb + ql * 2] = mrun;
      pml[mb + ql * 2 + 1] = lrun;
    }
  }
}

// ---------------- attention merge (exp2 domain, triangular slots) -----------
__launch_bounds__(256)
__global__ void attn_merge4(const bf16* __restrict__ pacc, const float* __restrict__ pml,
                            bf16* __restrict__ ctx) {
  const int qt = blockIdx.x, head = blockIdx.y;
  const int a = qt >> 3, bq = qt & 7;
  const int psum = qt + 8 * (a * (a - 1) / 2) + a * bq;
  const int slot0 = head * 288 + psum;
  const int nch = (qt >> 3) + 1;
  const size_t base = (size_t)slot0 * 2048;
  const size_t mb = (size_t)slot0 * 64;
  __shared__ float smem[32][65];
  for (int i = threadIdx.x; i < 2048; i += 256) {
    const int qi = i & 31, d = i >> 5;
    float m = -1e30f;
    for (int c = 0; c < nch; ++c) m = fmaxf(m, pml[mb + c * 64 + qi * 2]);
    float lsum = 0.f, o = 0.f;
    for (int c = 0; c < nch; ++c) {
      float e = exp2f(pml[mb + c * 64 + qi * 2] - m);
      lsum += pml[mb + c * 64 + qi * 2 + 1] * e;
      o += __bfloat162float(pacc[base + c * 2048 + d * 32 + qi]) * e;
    }
    smem[qi][d] = o / lsum;
  }
  __syncthreads();
  for (int i = threadIdx.x; i < 2048; i += 256) {
    const int qi = i >> 6, d = i & 63;
    ctx[(size_t)(qt * 32 + qi) * 960 + head * 64 + d] = __float2bfloat16(smem[qi][d]);
  }
}

// ---------------- launch ----------------------------------------------------
extern "C" void kernel_launch(void* const* d_in, const int* in_sizes, int n_in,
                              void* d_out, int out_size, void* d_ws, size_t ws_size,
                              hipStream_t stream) {
  const float* x  = (const float*)d_in[0];
  const float* wq = (const float*)d_in[1];
  const float* wk = (const float*)d_in[2];
  const float* wv = (const float*)d_in[3];
  const float* wo = (const float*)d_in[4];
  const float* wg = (const float*)d_in[5];
  const float* wu = (const float*)d_in[6];
  const float* wd = (const float*)d_in[7];
  const float* g1 = (const float*)d_in[8];
  const float* g2 = (const float*)d_in[9];
  float* out = (float*)d_out;

  char* ws = (char*)d_ws;
  bf16*   wT    = (bf16*)ws;                       // 0 .. 20,111,360
  bf16*   pacc  = (bf16*)(ws + 20111360);          // 17,694,720 (attn partials)
  __half* Ppart = (__half*)(ws + 20111360);        // 15,728,640 (wo partials, after merge)
  float*  pml   = (float*)(ws + 37806080);         // 1,105,920 (ends 38,912,000)
  bf16*   qr    = (bf16*)(ws + 38912000);          // 3,932,160
  bf16*   kr2   = (bf16*)(ws + 42844160);          // 1,310,720
  bf16*   vTb2  = (bf16*)(ws + 44154880);          // 1,310,720
  bf16*   ctx   = (bf16*)(ws + 45465600);          // 3,932,160 (ends 49,397,760)
  bf16*   actb  = (bf16*)(ws + 38912000);          // 10,485,760 (overlays qr..ctx, post-wo)
  bf16*   nbF   = (bf16*)(ws + 49397760);          // 3,932,160
  bf16*   nbK   = (bf16*)(ws + 53329920);          // 3,932,160
  float2* cst   = (float2*)(ws + 57262080);        // 524,288
  int*    items = (int*)(ws + 57786368);           // 17,280 (total ~57.8 MB)

  bf16* wqkvT = wT;            // 1600 x 960 (q|k|v rows)
  bf16* wkT  = wT + 921600;    // 640 x 960 (k|v rows) for kv GEMM
  bf16* woT  = wT + 1536000;   // 1024 x 960 (rows 960+ pad)
  bf16* wguT = wT + 2519040;   // 5120 x 960 interleaved [gate16|up16]
  bf16* wdT  = wT + 7434240;   // 1024 x 2560 (rows 960+ pad)

  dim3 blk(256);
  prep2_k<<<4708, blk, 0, stream>>>(wq, wk, wv, wo, wg, wu, wd,
                                    wqkvT, woT, wguT, wdT, cst, items, x, g1, nbF);
  gemm_qkv<<<dim3(13, 32), blk, 0, stream>>>(nbF, wqkvT, cst, qr, kr2, vTb2);
  attn_part8<<<4320, dim3(64), 0, stream>>>(qr, kr2, vTb2, items, pacc, pml);
  attn_merge4<<<dim3(64, 15), blk, 0, stream>>>(pacc, pml, ctx);
  gemm_sk<0><<<dim3(8, 16, 4), blk, 0, stream>>>(ctx, woT, Ppart, nullptr, 960, 960, 30, 8);
  rmsfuse2_k<<<2560, blk, 0, stream>>>(Ppart, x, g1, g2, out, nbF, nbK);
  ffnkv2_k<<<960, blk, 0, stream>>>(nbF, wguT, actb, nbK, wkT, out);
  gemm_sk<1><<<dim3(8, 16, 4), blk, 0, stream>>>(actb, wdT, nullptr, out, 960, 2560, 80, 20);
}

// Round 16
// 212.346 us; speedup vs baseline: 1.0089x; 1.0014x over previous
//
#include <hip/hip_runtime.h>
#include <hip/hip_bf16.h>
#include <hip/hip_fp16.h>

// TextEncoderBlock R16: kv tail-fill moved from ffn launch to the wd split-K
// launch (register-compatible paths: both gemm_core128+atomicAdd). ffn back to
// standalone natural-dispatch kernel (proven 40us / VGPR 72). 8 launches.
// B=1 L=2048 EMBD=960 FFN=2560 QH=15 KVH=5 HD=64

typedef __hip_bfloat16 bf16;
typedef __attribute__((ext_vector_type(8))) short bf16x8;
typedef __attribute__((ext_vector_type(4))) float f32x4;
typedef __attribute__((ext_vector_type(16))) float f32x16;

#define EPS 1.1920929e-07f
#define QSCL 0.1803368801111f  /* 0.125 * log2(e) */

__device__ __forceinline__ void gload_lds16(const bf16* g, bf16* l) {
  __builtin_amdgcn_global_load_lds(
      (const __attribute__((address_space(1))) unsigned int*)g,
      (__attribute__((address_space(3))) unsigned int*)l, 16, 0, 0);
}

__device__ __forceinline__ unsigned short f2bfu(float f) {
  __hip_bfloat16 b = __float2bfloat16(f);
  return *reinterpret_cast<unsigned short*>(&b);
}
__device__ __forceinline__ float bfu2f(unsigned short u) {
  return __uint_as_float(((unsigned int)u) << 16);
}
__device__ __forceinline__ float hu2f(unsigned short u) {
  __half_raw r; r.x = u;
  return __half2float((__half)r);
}
__device__ __forceinline__ unsigned int cvtpk(float lo, float hi_) {
  unsigned int r;
  asm("v_cvt_pk_bf16_f32 %0, %1, %2" : "=v"(r) : "v"(lo), "v"(hi_));
  return r;
}

// ---------------- shared 128x128 GEMM core (BK=32, dbuf, ptr-increment) -----
__device__ __forceinline__ void gemm_core128(const bf16* __restrict__ A,
    const bf16* __restrict__ BT, int K, int ks0, int ks1, int m0, int n0,
    bf16 (&sA)[2][4096], bf16 (&sB)[2][4096], f32x4 (&acc)[4][4]) {
  const int t = threadIdx.x, w = t >> 6, lane = t & 63;
  const int lg = lane >> 4, lr = lane & 15;
  const int wm = w >> 1, wn = w & 1;
  const int c0 = w * 128 + lane;
  const int c1 = c0 + 64;
  const bf16* pA0 = A + (size_t)(m0 + (c0 >> 2)) * K + ks0 * 32 + (c0 & 3) * 8;
  const bf16* pA1 = A + (size_t)(m0 + (c1 >> 2)) * K + ks0 * 32 + (c1 & 3) * 8;
  const bf16* pB0 = BT + (size_t)(n0 + (c0 >> 2)) * K + ks0 * 32 + (c0 & 3) * 8;
  const bf16* pB1 = BT + (size_t)(n0 + (c1 >> 2)) * K + ks0 * 32 + (c1 & 3) * 8;
  bf16* const dA0[2] = {&sA[0][c0 * 8], &sA[1][c0 * 8]};
  bf16* const dA1[2] = {&sA[0][c1 * 8], &sA[1][c1 * 8]};
  bf16* const dB0[2] = {&sB[0][c0 * 8], &sB[1][c0 * 8]};
  bf16* const dB1[2] = {&sB[0][c1 * 8], &sB[1][c1 * 8]};
  auto stage = [&](int buf) {
    gload_lds16(pA0, dA0[buf]);
    gload_lds16(pA1, dA1[buf]);
    gload_lds16(pB0, dB0[buf]);
    gload_lds16(pB1, dB1[buf]);
    pA0 += 32; pA1 += 32; pB0 += 32; pB1 += 32;
  };
  stage(0);
  __syncthreads();
  int cur = 0;
  for (int ks = ks0; ks < ks1; ++ks) {
    if (ks + 1 < ks1) stage(cur ^ 1);
    bf16x8 af[4], bfr[4];
#pragma unroll
    for (int mi = 0; mi < 4; ++mi)
      af[mi] = *reinterpret_cast<const bf16x8*>(&sA[cur][(wm * 64 + mi * 16 + lr) * 32 + lg * 8]);
#pragma unroll
    for (int ni = 0; ni < 4; ++ni)
      bfr[ni] = *reinterpret_cast<const bf16x8*>(&sB[cur][(wn * 64 + ni * 16 + lr) * 32 + lg * 8]);
#pragma unroll
    for (int mi = 0; mi < 4; ++mi)
#pragma unroll
      for (int ni = 0; ni < 4; ++ni)
        acc[mi][ni] = __builtin_amdgcn_mfma_f32_16x16x32_bf16(af[mi], bfr[ni], acc[mi][ni], 0, 0, 0);
    __syncthreads();
    cur ^= 1;
  }
}

// ---------------- fused prep: transposes + rope + items + first rmsnorm -----
__device__ void do_transpose(float (*tile)[65], const float* __restrict__ W,
                             bf16* __restrict__ WT, int K, int N, int bx, int by,
                             int map) {
  const int k0 = by * 64, n0 = bx * 64;
  const int tx = threadIdx.x & 63, ty = threadIdx.x >> 6;
#pragma unroll
  for (int i = 0; i < 16; ++i) {
    int r = ty + i * 4;
    tile[r][tx] = W[(size_t)(k0 + r) * N + n0 + tx];
  }
  __syncthreads();
#pragma unroll
  for (int i = 0; i < 16; ++i) {
    int r = ty + i * 4;
    int v = n0 + r;
    int row = (map == 0) ? v : ((v >> 4) << 5) + (v & 15) + (map == 2 ? 16 : 0);
    WT[(size_t)row * K + k0 + tx] = __float2bfloat16(tile[tx][r]);
  }
}

__launch_bounds__(256)
__global__ void prep2_k(const float* __restrict__ wq, const float* __restrict__ wk,
                        const float* __restrict__ wv, const float* __restrict__ wo,
                        const float* __restrict__ wg, const float* __restrict__ wu,
                        const float* __restrict__ wd, bf16* __restrict__ wqkvT,
                        bf16* __restrict__ woT, bf16* __restrict__ wguT,
                        bf16* __restrict__ wdT, float2* __restrict__ cstab,
                        int* __restrict__ items, const float* __restrict__ x,
                        const float* __restrict__ g1, bf16* __restrict__ nb) {
  __shared__ float tile[64][65];
  int b = blockIdx.x;
  if (b < 225) {
    do_transpose(tile, wq, wqkvT, 960, 960, b % 15, b / 15, 0);
  } else if (b < 300) {
    b -= 225;
    do_transpose(tile, wk, wqkvT + 921600, 960, 320, b % 5, b / 5, 0);
  } else if (b < 375) {
    b -= 300;
    do_transpose(tile, wv, wqkvT + 1228800, 960, 320, b % 5, b / 5, 0);
  } else if (b < 600) {
    b -= 375;
    do_transpose(tile, wo, woT, 960, 960, b % 15, b / 15, 0);
  } else if (b < 1200) {
    b -= 600;
    do_transpose(tile, wg, wguT, 960, 2560, b % 40, b / 40, 1);
  } else if (b < 1800) {
    b -= 1200;
    do_transpose(tile, wu, wguT, 960, 2560, b % 40, b / 40, 2);
  } else if (b < 2400) {
    b -= 1800;
    do_transpose(tile, wd, wdT, 2560, 960, b % 15, b / 15, 0);
  } else if (b < 2656) {
    const int idx = (b - 2400) * 256 + threadIdx.x;
    const int pos = idx >> 5, d = idx & 31;
    float inv = powf(10000.f, -(float)d * (1.f / 32.f));
    float rad = (float)pos * inv;
    cstab[idx] = make_float2(cosf(rad), sinf(rad));
  } else if (b < 2660) {
    const int idx = (b - 2656) * 256 + threadIdx.x;
    if (idx < 960) {
      const int head = idx >> 6, qt = idx & 63;
      const int a = qt >> 3, bq = qt & 7;
      const int psum = qt + 8 * (a * (a - 1) / 2) + a * bq;
      const int base = head * 288 + psum;
      const int nch = (qt >> 3) + 1;
      for (int c = 0; c < nch; ++c)
        items[base + c] = qt | (head << 8) | (c << 16);
    }
  } else {
    const int row = b - 2660;
    const float* xr = x + (size_t)row * 960;
    const int t = threadIdx.x;
    float4 v = {0.f, 0.f, 0.f, 0.f};
    float ss = 0.f;
    if (t < 240) {
      v = *reinterpret_cast<const float4*>(&xr[t * 4]);
      ss = v.x * v.x + v.y * v.y + v.z * v.z + v.w * v.w;
    }
#pragma unroll
    for (int off = 32; off; off >>= 1) ss += __shfl_down(ss, off);
    __shared__ float red[4];
    __shared__ float s_scale;
    if ((t & 63) == 0) red[t >> 6] = ss;
    __syncthreads();
    if (t == 0) {
      float tot = red[0] + red[1] + red[2] + red[3];
      s_scale = rsqrtf(tot * (1.f / 960.f) + EPS);
    }
    __syncthreads();
    if (t < 240) {
      const float sc = s_scale;
      const float4 gv = *reinterpret_cast<const float4*>(&g1[t * 4]);
      ushort4 o;
      o.x = f2bfu(v.x * sc * gv.x);
      o.y = f2bfu(v.y * sc * gv.y);
      o.z = f2bfu(v.z * sc * gv.z);
      o.w = f2bfu(v.w * sc * gv.w);
      *reinterpret_cast<ushort4*>(&nb[(size_t)row * 960 + t * 4]) = o;
    }
  }
}

// ---------------- rmsfuse2: out=sum(P)+x (residual2); dual norm; kv zero ----
__launch_bounds__(256)
__global__ void rmsfuse2_k(const __half* __restrict__ P, const float* __restrict__ x,
                           const float* __restrict__ g1, const float* __restrict__ g2,
                           float* __restrict__ outp, bf16* __restrict__ nbF,
                           bf16* __restrict__ nbK) {
  if (blockIdx.x >= 2048) {
    const int zb = blockIdx.x - 2048;
    for (int i = zb * 256 + threadIdx.x; i < 327680; i += 131072) {
      float4 z = {0.f, 0.f, 0.f, 0.f};
      *reinterpret_cast<float4*>(&outp[1966080 + (size_t)i * 4]) = z;
    }
    return;
  }
  const int row = blockIdx.x;
  const int t = threadIdx.x;
  float4 v = {0.f, 0.f, 0.f, 0.f};
  float ss = 0.f;
  if (t < 240) {
    const size_t e = (size_t)row * 960 + t * 4;
    v = *reinterpret_cast<const float4*>(&x[e]);
#pragma unroll
    for (int s = 0; s < 4; ++s) {
      ushort4 pa = *reinterpret_cast<const ushort4*>(&P[(size_t)s * 1966080 + e]);
      v.x += hu2f(pa.x); v.y += hu2f(pa.y); v.z += hu2f(pa.z); v.w += hu2f(pa.w);
    }
    ss = v.x * v.x + v.y * v.y + v.z * v.z + v.w * v.w;
  }
#pragma unroll
  for (int off = 32; off; off >>= 1) ss += __shfl_down(ss, off);
  __shared__ float red[4];
  __shared__ float s_scale;
  if ((t & 63) == 0) red[t >> 6] = ss;
  __syncthreads();
  if (t == 0) {
    float tot = red[0] + red[1] + red[2] + red[3];
    s_scale = rsqrtf(tot * (1.f / 960.f) + EPS);
  }
  __syncthreads();
  if (t < 240) {
    const size_t e = (size_t)row * 960 + t * 4;
    const float sc = s_scale;
    *reinterpret_cast<float4*>(&outp[e]) = v;
    const float4 gv2 = *reinterpret_cast<const float4*>(&g2[t * 4]);
    const float4 gv1 = *reinterpret_cast<const float4*>(&g1[t * 4]);
    ushort4 oF, oK;
    oF.x = f2bfu(v.x * sc * gv2.x); oF.y = f2bfu(v.y * sc * gv2.y);
    oF.z = f2bfu(v.z * sc * gv2.z); oF.w = f2bfu(v.w * sc * gv2.w);
    oK.x = f2bfu(v.x * sc * gv1.x); oK.y = f2bfu(v.y * sc * gv1.y);
    oK.z = f2bfu(v.z * sc * gv1.z); oK.w = f2bfu(v.w * sc * gv1.w);
    *reinterpret_cast<ushort4*>(&nbF[e]) = oF;
    *reinterpret_cast<ushort4*>(&nbK[e]) = oK;
  }
}

// ---------------- FFN GEMM 128x128 (natural dispatch), SwiGLU epilogue ------
__launch_bounds__(256)
__global__ void gemm_ffn(const bf16* __restrict__ A, const bf16* __restrict__ BT,
                         bf16* __restrict__ actb) {
  __shared__ __align__(16) bf16 sA[2][4096];
  __shared__ __align__(16) bf16 sB[2][4096];
  const int t = threadIdx.x, w = t >> 6, lane = t & 63;
  const int lg = lane >> 4, lr = lane & 15;
  const int wm = w >> 1, wn = w & 1;
  const int m0 = blockIdx.y * 128, n0 = blockIdx.x * 128;
  f32x4 acc[4][4] = {};
  gemm_core128(A, BT, 960, 0, 30, m0, n0, sA, sB, acc);

  const int colbase = n0 + wn * 64;
#pragma unroll
  for (int mi = 0; mi < 4; ++mi) {
    const int row = m0 + wm * 64 + mi * 16 + lg * 4;
#pragma unroll
    for (int p = 0; p < 2; ++p) {
      const int oc = ((colbase >> 5) + p) * 16 + lr;
#pragma unroll
      for (int r = 0; r < 4; ++r) {
        float gf = acc[mi][2 * p][r], uf = acc[mi][2 * p + 1][r];
        float s = gf / (1.f + __expf(-gf));
        actb[(size_t)(row + r) * 2560 + oc] = __float2bfloat16(s * uf);
      }
    }
  }
}

// ---------------- wo split-K GEMM: fp16 partials ----------------------------
__launch_bounds__(256)
__global__ void gemm_wo(const bf16* __restrict__ A, const bf16* __restrict__ BT,
                        __half* __restrict__ P) {
  __shared__ __align__(16) bf16 sA[2][4096];
  __shared__ __align__(16) bf16 sB[2][4096];
  const int lid = blockIdx.x;
  const int sid = (lid & 7) * 64 + (lid >> 3);   // 512 blocks
  const int bx = sid % 8, by = (sid / 8) % 16, bz = sid / 128;
  const int t = threadIdx.x, w = t >> 6, lane = t & 63;
  const int lg = lane >> 4, lr = lane & 15;
  const int wm = w >> 1, wn = w & 1;
  const int m0 = by * 128, n0 = bx * 128;
  const int ks0 = bz * 8, ks1 = ks0 + 8;  // 30 steps: last chunk short
  f32x4 acc[4][4] = {};
  gemm_core128(A, BT, 960, ks0, min(ks1, 30), m0, n0, sA, sB, acc);

  __half* Ps = P + (size_t)bz * 2048 * 960;
#pragma unroll
  for (int mi = 0; mi < 4; ++mi) {
    const int row = m0 + wm * 64 + mi * 16 + lg * 4;
#pragma unroll
    for (int ni = 0; ni < 4; ++ni) {
      const int col = n0 + wn * 64 + ni * 16 + lr;
      if (col < 960) {
#pragma unroll
        for (int r = 0; r < 4; ++r)
          Ps[(size_t)(row + r) * 960 + col] = __float2half(acc[mi][ni][r]);
      }
    }
  }
}

// ---------------- merged wd + kv split-K (both atomicAdd into out) ----------
// grid 832: blocks 0..511 wd (8x16x4 swizzled, N=960 K=2560);
//           blocks 512..831 kv (5x16x4 swizzled, N=640 K=960, split output).
__launch_bounds__(256)
__global__ void wdkv_k(const bf16* __restrict__ actb, const bf16* __restrict__ wdT,
                       const bf16* __restrict__ nbK, const bf16* __restrict__ wkT,
                       float* __restrict__ outp) {
  __shared__ __align__(16) bf16 sA[2][4096];
  __shared__ __align__(16) bf16 sB[2][4096];
  const int b = blockIdx.x;
  const int t = threadIdx.x, w = t >> 6, lane = t & 63;
  const int lg = lane >> 4, lr = lane & 15;
  const int wm = w >> 1, wn = w & 1;
  f32x4 acc[4][4] = {};

  if (b < 512) {
    // ---- wd: N=960, K=2560, split-K x4 (20 steps each) ----
    const int sid = (b & 7) * 64 + (b >> 3);
    const int bx = sid % 8, by = (sid / 8) % 16, bz = sid / 128;
    const int m0 = by * 128, n0 = bx * 128;
    gemm_core128(actb, wdT, 2560, bz * 20, bz * 20 + 20, m0, n0, sA, sB, acc);
#pragma unroll
    for (int mi = 0; mi < 4; ++mi) {
      const int row = m0 + wm * 64 + mi * 16 + lg * 4;
#pragma unroll
      for (int ni = 0; ni < 4; ++ni) {
        const int col = n0 + wn * 64 + ni * 16 + lr;
        if (col < 960) {
#pragma unroll
          for (int r = 0; r < 4; ++r)
            atomicAdd(&outp[(size_t)(row + r) * 960 + col], acc[mi][ni][r]);
        }
      }
    }
  } else {
    // ---- kv: N=640, K=960, split-K x4 (8 steps, last chunk 6) ----
    const int lb = b - 512;
    const int sid = (lb & 7) * 40 + (lb >> 3);
    const int bx = sid % 5, by = (sid / 5) % 16, bz = sid / 80;
    const int m0 = by * 128, n0 = bx * 128;
    gemm_core128(nbK, wkT, 960, bz * 8, min(bz * 8 + 8, 30), m0, n0, sA, sB, acc);
#pragma unroll
    for (int mi = 0; mi < 4; ++mi) {
      const int row = m0 + wm * 64 + mi * 16 + lg * 4;
#pragma unroll
      for (int ni = 0; ni < 4; ++ni) {
        const int col = n0 + wn * 64 + ni * 16 + lr;
#pragma unroll
        for (int r = 0; r < 4; ++r) {
          const int rr = row + r;
          float* dst = (col < 320) ? outp + 1966080 + (size_t)rr * 320 + col
                                   : outp + 2621440 + (size_t)rr * 320 + (col - 320);
          atomicAdd(dst, acc[mi][ni][r]);
        }
      }
    }
  }
}

// ---------------- QKV GEMM 64x128, fused RoPE + fragment-order K/V ----------
__launch_bounds__(256)
__global__ void gemm_qkv(const bf16* __restrict__ A, const bf16* __restrict__ BT,
                         const float2* __restrict__ cstab, bf16* __restrict__ qr,
                         bf16* __restrict__ kr2, bf16* __restrict__ vTb2) {
  const int N = 1600, K = 960;
  __shared__ __align__(16) bf16 sA[2][64 * 32];
  __shared__ __align__(16) bf16 sB[2][128 * 32];
  const int t = threadIdx.x, w = t >> 6, lane = t & 63;
  const int lg = lane >> 4, lr = lane & 15;
  const int wm = w >> 1, wn = w & 1;
  const int m0 = blockIdx.y * 64, n0 = blockIdx.x * 128;
  f32x4 acc[2][4] = {};
  const int nsteps = K / 32;

  const int cA = t, cB0 = t, cB1 = t + 256;
  const bf16* pA = A + (size_t)(m0 + (cA >> 2)) * K + (cA & 3) * 8;
  int brow0 = n0 + (cB0 >> 2); if (brow0 >= N) brow0 = N - 1;
  int brow1 = n0 + (cB1 >> 2); if (brow1 >= N) brow1 = N - 1;
  const bf16* pB0 = BT + (size_t)brow0 * K + (cB0 & 3) * 8;
  const bf16* pB1 = BT + (size_t)brow1 * K + (cB1 & 3) * 8;
  auto stage = [&](int buf) {
    gload_lds16(pA, &sA[buf][cA * 8]);
    gload_lds16(pB0, &sB[buf][cB0 * 8]);
    gload_lds16(pB1, &sB[buf][cB1 * 8]);
    pA += 32; pB0 += 32; pB1 += 32;
  };

  stage(0);
  __syncthreads();
  int cur = 0;
  for (int ks = 0; ks < nsteps; ++ks) {
    if (ks + 1 < nsteps) stage(cur ^ 1);
    bf16x8 af[2], bfr[4];
#pragma unroll
    for (int mi = 0; mi < 2; ++mi)
      af[mi] = *reinterpret_cast<const bf16x8*>(&sA[cur][(wm * 32 + mi * 16 + lr) * 32 + lg * 8]);
#pragma unroll
    for (int ni = 0; ni < 4; ++ni)
      bfr[ni] = *reinterpret_cast<const bf16x8*>(&sB[cur][(wn * 64 + ni * 16 + lr) * 32 + lg * 8]);
#pragma unroll
    for (int mi = 0; mi < 2; ++mi)
#pragma unroll
      for (int ni = 0; ni < 4; ++ni)
        acc[mi][ni] = __builtin_amdgcn_mfma_f32_16x16x32_bf16(af[mi], bfr[ni], acc[mi][ni], 0, 0, 0);
    __syncthreads();
    cur ^= 1;
  }

  const int colbase = n0 + wn * 64;
  if (colbase >= 1600) return;
  if (colbase < 960) {
#pragma unroll
    for (int mi = 0; mi < 2; ++mi) {
      const int row = m0 + wm * 32 + mi * 16 + lg * 4;
#pragma unroll
      for (int ni = 0; ni < 2; ++ni) {
        const int d = ni * 16 + lr;
#pragma unroll
        for (int r = 0; r < 4; ++r) {
          const int pos = row + r;
          float2 cs = cstab[pos * 32 + d];
          float x1 = acc[mi][ni][r], x2 = acc[mi][ni + 2][r];
          qr[(size_t)pos * 960 + colbase + d] =
              __float2bfloat16((x1 * cs.x - x2 * cs.y) * QSCL);
          qr[(size_t)pos * 960 + colbase + d + 32] =
              __float2bfloat16((x2 * cs.x + x1 * cs.y) * QSCL);
        }
      }
    }
  } else if (colbase < 1280) {
    const int cb = colbase - 960;
    const int kvh = cb >> 6;
#pragma unroll
    for (int mi = 0; mi < 2; ++mi) {
      const int row = m0 + wm * 32 + mi * 16 + lg * 4;
#pragma unroll
      for (int ni = 0; ni < 2; ++ni) {
        const int d = ni * 16 + lr;
#pragma unroll
        for (int r = 0; r < 4; ++r) {
          const int pos = row + r;
          float2 cs = cstab[pos * 32 + d];
          float v1 = acc[mi][ni][r] * cs.x - acc[mi][ni + 2][r] * cs.y;
          float v2 = acc[mi][ni + 2][r] * cs.x + acc[mi][ni][r] * cs.y;
          const size_t blk = ((size_t)(pos >> 5) * 5 + kvh) * 2048;
          const int dl1 = d, dl2 = d + 32;
          kr2[blk + (size_t)(((dl1 >> 4) << 6) + (((dl1 >> 3) & 1) << 5) + (pos & 31)) * 8 + (dl1 & 7)] =
              __float2bfloat16(v1);
          kr2[blk + (size_t)(((dl2 >> 4) << 6) + (((dl2 >> 3) & 1) << 5) + (pos & 31)) * 8 + (dl2 & 7)] =
              __float2bfloat16(v2);
        }
      }
    }
  } else {
#pragma unroll
    for (int mi = 0; mi < 2; ++mi) {
      const int row = m0 + wm * 32 + mi * 16 + lg * 4;
#pragma unroll
      for (int ni = 0; ni < 4; ++ni) {
        const int vc = colbase - 1280 + ni * 16 + lr;
        ushort4 pk;
        pk.x = f2bfu(acc[mi][ni][0]);
        pk.y = f2bfu(acc[mi][ni][1]);
        pk.z = f2bfu(acc[mi][ni][2]);
        pk.w = f2bfu(acc[mi][ni][3]);
        const int db = (vc >> 5) & 1, dq = vc & 31;
        const int pb = (row >> 4) & 1, h2 = (row >> 3) & 1;
        const size_t blk = ((size_t)(row >> 5) * 5 + (vc >> 6)) * 2048;
        *reinterpret_cast<ushort4*>(
            &vTb2[blk + (size_t)(((db * 2 + pb) << 6) + (h2 << 5) + dq) * 8 + (row & 7)]) = pk;
      }
    }
  }
}

// ---------------- persistent-wave flash attention (1 item / block) ----------
__launch_bounds__(64)
__global__ void attn_part8(const bf16* __restrict__ q, const bf16* __restrict__ kr2,
                           const bf16* __restrict__ vTb2, const int* __restrict__ items,
                           bf16* __restrict__ pacc, float* __restrict__ pml) {
  const int lane = threadIdx.x & 63;
  const int ql = lane & 31, hi = lane >> 5;
  const int kvoff = 4 * hi;

  {
    const int it = blockIdx.x;
    const int v = items[it];
    const int qt = v & 255, head = (v >> 8) & 255, c = v >> 16;
    const int q0 = qt * 32;
    const int kvh = head / 3;
    const int t0 = c * 8, t1 = min(t0 + 8, qt + 1);
    const int qrow = q0 + ql;

    bf16x8 qf0 = *reinterpret_cast<const bf16x8*>(&q[(size_t)(q0 + ql) * 960 + head * 64 + hi * 8]);
    bf16x8 qf1 = *reinterpret_cast<const bf16x8*>(&q[(size_t)(q0 + ql) * 960 + head * 64 + 16 + hi * 8]);
    bf16x8 qf2 = *reinterpret_cast<const bf16x8*>(&q[(size_t)(q0 + ql) * 960 + head * 64 + 32 + hi * 8]);
    bf16x8 qf3 = *reinterpret_cast<const bf16x8*>(&q[(size_t)(q0 + ql) * 960 + head * 64 + 48 + hi * 8]);

    f32x16 acc0 = {}, acc1 = {};
    float mrun = -1e30f, lrun = 0.f;
    const bf16* kp = kr2 + ((size_t)t0 * 5 + kvh) * 2048 + (hi * 32 + ql) * 8;
    const bf16* vp = vTb2 + ((size_t)t0 * 5 + kvh) * 2048 + (hi * 32 + ql) * 8;

    for (int kb = t0; kb < t1; ++kb) {
      bf16x8 kc0 = *reinterpret_cast<const bf16x8*>(kp);
      bf16x8 kc1 = *reinterpret_cast<const bf16x8*>(kp + 512);
      bf16x8 kc2 = *reinterpret_cast<const bf16x8*>(kp + 1024);
      bf16x8 kc3 = *reinterpret_cast<const bf16x8*>(kp + 1536);
      bf16x8 vc0 = *reinterpret_cast<const bf16x8*>(vp);
      bf16x8 vc1 = *reinterpret_cast<const bf16x8*>(vp + 512);
      bf16x8 vc2 = *reinterpret_cast<const bf16x8*>(vp + 1024);
      bf16x8 vc3 = *reinterpret_cast<const bf16x8*>(vp + 1536);

      __builtin_amdgcn_s_setprio(1);
      f32x16 sa = {}, sb = {};
      sa = __builtin_amdgcn_mfma_f32_32x32x16_bf16(kc0, qf0, sa, 0, 0, 0);
      sb = __builtin_amdgcn_mfma_f32_32x32x16_bf16(kc1, qf1, sb, 0, 0, 0);
      sa = __builtin_amdgcn_mfma_f32_32x32x16_bf16(kc2, qf2, sa, 0, 0, 0);
      sb = __builtin_amdgcn_mfma_f32_32x32x16_bf16(kc3, qf3, sb, 0, 0, 0);
      __builtin_amdgcn_s_setprio(0);

      if (kb == qt) {
        const int kvb = kb * 32;
#pragma unroll
        for (int r = 0; r < 16; ++r) {
          const int kv = kvb + kvoff + (r & 3) + 8 * (r >> 2);
          float sv = sa[r] + sb[r];
          sa[r] = (kv > qrow) ? -1e30f : sv;
        }
      } else {
#pragma unroll
        for (int r = 0; r < 16; ++r) sa[r] += sb[r];
      }

      float m0_ = fmaxf(fmaxf(sa[0], sa[1]), fmaxf(sa[2], sa[3]));
      float m1_ = fmaxf(fmaxf(sa[4], sa[5]), fmaxf(sa[6], sa[7]));
      float m2_ = fmaxf(fmaxf(sa[8], sa[9]), fmaxf(sa[10], sa[11]));
      float m3_ = fmaxf(fmaxf(sa[12], sa[13]), fmaxf(sa[14], sa[15]));
      float tm = fmaxf(fmaxf(m0_, m1_), fmaxf(m2_, m3_));
      tm = fmaxf(tm, __shfl_xor(tm, 32));
      if (__any(tm > mrun + 11.5f)) {
        const float mn = fmaxf(mrun, tm);
        const float ef = exp2f(mrun - mn);
        mrun = mn;
#pragma unroll
        for (int r = 0; r < 16; ++r) { acc0[r] *= ef; acc1[r] *= ef; }
        lrun *= ef;
      }
#pragma unroll
      for (int r = 0; r < 16; ++r) sa[r] = exp2f(sa[r] - mrun);
      float t0_ = (sa[0] + sa[1]) + (sa[2] + sa[3]);
      float t1_ = (sa[4] + sa[5]) + (sa[6] + sa[7]);
      float t2_ = (sa[8] + sa[9]) + (sa[10] + sa[11]);
      float t3_ = (sa[12] + sa[13]) + (sa[14] + sa[15]);
      float ts = (t0_ + t1_) + (t2_ + t3_);
      ts += __shfl_xor(ts, 32);
      lrun += ts;

      unsigned int a0 = cvtpk(sa[0], sa[1]), a1 = cvtpk(sa[2], sa[3]);
      unsigned int a2 = cvtpk(sa[4], sa[5]), a3 = cvtpk(sa[6], sa[7]);
      unsigned int b0 = cvtpk(sa[8], sa[9]), b1 = cvtpk(sa[10], sa[11]);
      unsigned int b2 = cvtpk(sa[12], sa[13]), b3 = cvtpk(sa[14], sa[15]);
      asm volatile("v_permlane32_swap_b32 %0, %1" : "+v"(a0), "+v"(a2));
      asm volatile("v_permlane32_swap_b32 %0, %1" : "+v"(a1), "+v"(a3));
      asm volatile("v_permlane32_swap_b32 %0, %1" : "+v"(b0), "+v"(b2));
      asm volatile("v_permlane32_swap_b32 %0, %1" : "+v"(b1), "+v"(b3));
      union { unsigned int u[4]; bf16x8 v; } f0, f1;
      f0.u[0] = a0; f0.u[1] = a1; f0.u[2] = a2; f0.u[3] = a3;
      f1.u[0] = b0; f1.u[1] = b1; f1.u[2] = b2; f1.u[3] = b3;

      __builtin_amdgcn_s_setprio(1);
      acc0 = __builtin_amdgcn_mfma_f32_32x32x16_bf16(vc0, f0.v, acc0, 0, 0, 0);
      acc1 = __builtin_amdgcn_mfma_f32_32x32x16_bf16(vc2, f0.v, acc1, 0, 0, 0);
      acc0 = __builtin_amdgcn_mfma_f32_32x32x16_bf16(vc1, f1.v, acc0, 0, 0, 0);
      acc1 = __builtin_amdgcn_mfma_f32_32x32x16_bf16(vc3, f1.v, acc1, 0, 0, 0);
      __builtin_amdgcn_s_setprio(0);

      kp += 5 * 2048;
      vp += 5 * 2048;
    }

    const size_t base = (size_t)it * 2048;
#pragma unroll
    for (int r = 0; r < 16; ++r) {
      const int row = (r & 3) + 8 * (r >> 2) + kvoff;
      pacc[base + (size_t)row * 32 + ql] = __float2bfloat16(acc0[r]);
      pacc[base + (size_t)(row + 32) * 32 + ql] = __float2bfloat16(acc1[r]);
    }
    const size_t mb = (size_t)it * 64;
    if (!hi) {
      pml[mb + ql * 2] = mrun;
      pml[mb + ql * 2 + 1] = lrun;
    }
  }
}

// ---------------- attention merge (exp2 domain, triangular slots) -----------
__launch_bounds__(256)
__global__ void attn_merge4(const bf16* __restrict__ pacc, const float* __restrict__ pml,
                            bf16* __restrict__ ctx) {
  const int qt = blockIdx.x, head = blockIdx.y;
  const int a = qt >> 3, bq = qt & 7;
  const int psum = qt + 8 * (a * (a - 1) / 2) + a * bq;
  const int slot0 = head * 288 + psum;
  const int nch = (qt >> 3) + 1;
  const size_t base = (size_t)slot0 * 2048;
  const size_t mb = (size_t)slot0 * 64;
  __shared__ float smem[32][65];
  for (int i = threadIdx.x; i < 2048; i += 256) {
    const int qi = i & 31, d = i >> 5;
    float m = -1e30f;
    for (int c = 0; c < nch; ++c) m = fmaxf(m, pml[mb + c * 64 + qi * 2]);
    float lsum = 0.f, o = 0.f;
    for (int c = 0; c < nch; ++c) {
      float e = exp2f(pml[mb + c * 64 + qi * 2] - m);
      lsum += pml[mb + c * 64 + qi * 2 + 1] * e;
      o += __bfloat162float(pacc[base + c * 2048 + d * 32 + qi]) * e;
    }
    smem[qi][d] = o / lsum;
  }
  __syncthreads();
  for (int i = threadIdx.x; i < 2048; i += 256) {
    const int qi = i >> 6, d = i & 63;
    ctx[(size_t)(qt * 32 + qi) * 960 + head * 64 + d] = __float2bfloat16(smem[qi][d]);
  }
}

// ---------------- launch ----------------------------------------------------
extern "C" void kernel_launch(void* const* d_in, const int* in_sizes, int n_in,
                              void* d_out, int out_size, void* d_ws, size_t ws_size,
                              hipStream_t stream) {
  const float* x  = (const float*)d_in[0];
  const float* wq = (const float*)d_in[1];
  const float* wk = (const float*)d_in[2];
  const float* wv = (const float*)d_in[3];
  const float* wo = (const float*)d_in[4];
  const float* wg = (const float*)d_in[5];
  const float* wu = (const float*)d_in[6];
  const float* wd = (const float*)d_in[7];
  const float* g1 = (const float*)d_in[8];
  const float* g2 = (const float*)d_in[9];
  float* out = (float*)d_out;

  char* ws = (char*)d_ws;
  bf16*   wT    = (bf16*)ws;                       // 0 .. 20,111,360
  bf16*   pacc  = (bf16*)(ws + 20111360);          // 17,694,720 (attn partials)
  __half* Ppart = (__half*)(ws + 20111360);        // 15,728,640 (wo partials, after merge)
  float*  pml   = (float*)(ws + 37806080);         // 1,105,920 (ends 38,912,000)
  bf16*   qr    = (bf16*)(ws + 38912000);          // 3,932,160
  bf16*   kr2   = (bf16*)(ws + 42844160);          // 1,310,720
  bf16*   vTb2  = (bf16*)(ws + 44154880);          // 1,310,720
  bf16*   ctx   = (bf16*)(ws + 45465600);          // 3,932,160 (ends 49,397,760)
  bf16*   actb  = (bf16*)(ws + 38912000);          // 10,485,760 (overlays qr..ctx, post-wo)
  bf16*   nbF   = (bf16*)(ws + 49397760);          // 3,932,160
  bf16*   nbK   = (bf16*)(ws + 53329920);          // 3,932,160
  float2* cst   = (float2*)(ws + 57262080);        // 524,288
  int*    items = (int*)(ws + 57786368);           // 17,280 (total ~57.8 MB)

  bf16* wqkvT = wT;            // 1600 x 960 (q|k|v rows)
  bf16* wkT  = wT + 921600;    // 640 x 960 (k|v rows) for kv GEMM
  bf16* woT  = wT + 1536000;   // 1024 x 960 (rows 960+ pad)
  bf16* wguT = wT + 2519040;   // 5120 x 960 interleaved [gate16|up16]
  bf16* wdT  = wT + 7434240;   // 1024 x 2560 (rows 960+ pad)

  dim3 blk(256);
  prep2_k<<<4708, blk, 0, stream>>>(wq, wk, wv, wo, wg, wu, wd,
                                    wqkvT, woT, wguT, wdT, cst, items, x, g1, nbF);
  gemm_qkv<<<dim3(13, 32), blk, 0, stream>>>(nbF, wqkvT, cst, qr, kr2, vTb2);
  attn_part8<<<4320, dim3(64), 0, stream>>>(qr, kr2, vTb2, items, pacc, pml);
  attn_merge4<<<dim3(64, 15), blk, 0, stream>>>(pacc, pml, ctx);
  gemm_wo<<<512, blk, 0, stream>>>(ctx, woT, Ppart);
  rmsfuse2_k<<<2560, blk, 0, stream>>>(Ppart, x, g1, g2, out, nbF, nbK);
  gemm_ffn<<<dim3(40, 16), blk, 0, stream>>>(nbF, wguT, actb);
  wdkv_k<<<832, blk, 0, stream>>>(actb, wdT, nbK, wkT, out);
}

// Round 17
// 194.555 us; speedup vs baseline: 1.1012x; 1.0914x over previous
//
#include <hip/hip_runtime.h>
#include <hip/hip_bf16.h>
#include <hip/hip_fp16.h>

// TextEncoderBlock R17: revert to R11's proven fp16-partials+reduce structure
// (wd/kv atomics were a hidden +20us regression carried since R12). Keeps
// prep2 merge, 4320-block permlane attention, pointer-increment GEMM core.
// B=1 L=2048 EMBD=960 FFN=2560 QH=15 KVH=5 HD=64

typedef __hip_bfloat16 bf16;
typedef __attribute__((ext_vector_type(8))) short bf16x8;
typedef __attribute__((ext_vector_type(4))) float f32x4;
typedef __attribute__((ext_vector_type(16))) float f32x16;

#define EPS 1.1920929e-07f
#define QSCL 0.1803368801111f  /* 0.125 * log2(e) */

__device__ __forceinline__ void gload_lds16(const bf16* g, bf16* l) {
  __builtin_amdgcn_global_load_lds(
      (const __attribute__((address_space(1))) unsigned int*)g,
      (__attribute__((address_space(3))) unsigned int*)l, 16, 0, 0);
}

__device__ __forceinline__ unsigned short f2bfu(float f) {
  __hip_bfloat16 b = __float2bfloat16(f);
  return *reinterpret_cast<unsigned short*>(&b);
}
__device__ __forceinline__ float bfu2f(unsigned short u) {
  return __uint_as_float(((unsigned int)u) << 16);
}
__device__ __forceinline__ float hu2f(unsigned short u) {
  __half_raw r; r.x = u;
  return __half2float((__half)r);
}
__device__ __forceinline__ unsigned int cvtpk(float lo, float hi_) {
  unsigned int r;
  asm("v_cvt_pk_bf16_f32 %0, %1, %2" : "=v"(r) : "v"(lo), "v"(hi_));
  return r;
}

// ---------------- shared 128x128 GEMM core (BK=32, dbuf, ptr-increment) -----
__device__ __forceinline__ void gemm_core128(const bf16* __restrict__ A,
    const bf16* __restrict__ BT, int K, int ks0, int ks1, int m0, int n0,
    bf16 (&sA)[2][4096], bf16 (&sB)[2][4096], f32x4 (&acc)[4][4]) {
  const int t = threadIdx.x, w = t >> 6, lane = t & 63;
  const int lg = lane >> 4, lr = lane & 15;
  const int wm = w >> 1, wn = w & 1;
  const int c0 = w * 128 + lane;
  const int c1 = c0 + 64;
  const bf16* pA0 = A + (size_t)(m0 + (c0 >> 2)) * K + ks0 * 32 + (c0 & 3) * 8;
  const bf16* pA1 = A + (size_t)(m0 + (c1 >> 2)) * K + ks0 * 32 + (c1 & 3) * 8;
  const bf16* pB0 = BT + (size_t)(n0 + (c0 >> 2)) * K + ks0 * 32 + (c0 & 3) * 8;
  const bf16* pB1 = BT + (size_t)(n0 + (c1 >> 2)) * K + ks0 * 32 + (c1 & 3) * 8;
  bf16* const dA0[2] = {&sA[0][c0 * 8], &sA[1][c0 * 8]};
  bf16* const dA1[2] = {&sA[0][c1 * 8], &sA[1][c1 * 8]};
  bf16* const dB0[2] = {&sB[0][c0 * 8], &sB[1][c0 * 8]};
  bf16* const dB1[2] = {&sB[0][c1 * 8], &sB[1][c1 * 8]};
  auto stage = [&](int buf) {
    gload_lds16(pA0, dA0[buf]);
    gload_lds16(pA1, dA1[buf]);
    gload_lds16(pB0, dB0[buf]);
    gload_lds16(pB1, dB1[buf]);
    pA0 += 32; pA1 += 32; pB0 += 32; pB1 += 32;
  };
  stage(0);
  __syncthreads();
  int cur = 0;
  for (int ks = ks0; ks < ks1; ++ks) {
    if (ks + 1 < ks1) stage(cur ^ 1);
    bf16x8 af[4], bfr[4];
#pragma unroll
    for (int mi = 0; mi < 4; ++mi)
      af[mi] = *reinterpret_cast<const bf16x8*>(&sA[cur][(wm * 64 + mi * 16 + lr) * 32 + lg * 8]);
#pragma unroll
    for (int ni = 0; ni < 4; ++ni)
      bfr[ni] = *reinterpret_cast<const bf16x8*>(&sB[cur][(wn * 64 + ni * 16 + lr) * 32 + lg * 8]);
#pragma unroll
    for (int mi = 0; mi < 4; ++mi)
#pragma unroll
      for (int ni = 0; ni < 4; ++ni)
        acc[mi][ni] = __builtin_amdgcn_mfma_f32_16x16x32_bf16(af[mi], bfr[ni], acc[mi][ni], 0, 0, 0);
    __syncthreads();
    cur ^= 1;
  }
}

// ---------------- fused prep: transposes + rope + items + first rmsnorm -----
__device__ void do_transpose(float (*tile)[65], const float* __restrict__ W,
                             bf16* __restrict__ WT, int K, int N, int bx, int by,
                             int map) {
  const int k0 = by * 64, n0 = bx * 64;
  const int tx = threadIdx.x & 63, ty = threadIdx.x >> 6;
#pragma unroll
  for (int i = 0; i < 16; ++i) {
    int r = ty + i * 4;
    tile[r][tx] = W[(size_t)(k0 + r) * N + n0 + tx];
  }
  __syncthreads();
#pragma unroll
  for (int i = 0; i < 16; ++i) {
    int r = ty + i * 4;
    int v = n0 + r;
    int row = (map == 0) ? v : ((v >> 4) << 5) + (v & 15) + (map == 2 ? 16 : 0);
    WT[(size_t)row * K + k0 + tx] = __float2bfloat16(tile[tx][r]);
  }
}

__launch_bounds__(256)
__global__ void prep2_k(const float* __restrict__ wq, const float* __restrict__ wk,
                        const float* __restrict__ wv, const float* __restrict__ wo,
                        const float* __restrict__ wg, const float* __restrict__ wu,
                        const float* __restrict__ wd, bf16* __restrict__ wqkvT,
                        bf16* __restrict__ woT, bf16* __restrict__ wguT,
                        bf16* __restrict__ wdT, float2* __restrict__ cstab,
                        int* __restrict__ items, const float* __restrict__ x,
                        const float* __restrict__ g1, bf16* __restrict__ nb) {
  __shared__ float tile[64][65];
  int b = blockIdx.x;
  if (b < 225) {
    do_transpose(tile, wq, wqkvT, 960, 960, b % 15, b / 15, 0);
  } else if (b < 300) {
    b -= 225;
    do_transpose(tile, wk, wqkvT + 921600, 960, 320, b % 5, b / 5, 0);
  } else if (b < 375) {
    b -= 300;
    do_transpose(tile, wv, wqkvT + 1228800, 960, 320, b % 5, b / 5, 0);
  } else if (b < 600) {
    b -= 375;
    do_transpose(tile, wo, woT, 960, 960, b % 15, b / 15, 0);
  } else if (b < 1200) {
    b -= 600;
    do_transpose(tile, wg, wguT, 960, 2560, b % 40, b / 40, 1);
  } else if (b < 1800) {
    b -= 1200;
    do_transpose(tile, wu, wguT, 960, 2560, b % 40, b / 40, 2);
  } else if (b < 2400) {
    b -= 1800;
    do_transpose(tile, wd, wdT, 2560, 960, b % 15, b / 15, 0);
  } else if (b < 2656) {
    const int idx = (b - 2400) * 256 + threadIdx.x;
    const int pos = idx >> 5, d = idx & 31;
    float inv = powf(10000.f, -(float)d * (1.f / 32.f));
    float rad = (float)pos * inv;
    cstab[idx] = make_float2(cosf(rad), sinf(rad));
  } else if (b < 2660) {
    const int idx = (b - 2656) * 256 + threadIdx.x;
    if (idx < 960) {
      const int head = idx >> 6, qt = idx & 63;
      const int a = qt >> 3, bq = qt & 7;
      const int psum = qt + 8 * (a * (a - 1) / 2) + a * bq;
      const int base = head * 288 + psum;
      const int nch = (qt >> 3) + 1;
      for (int c = 0; c < nch; ++c)
        items[base + c] = qt | (head << 8) | (c << 16);
    }
  } else {
    const int row = b - 2660;
    const float* xr = x + (size_t)row * 960;
    const int t = threadIdx.x;
    float4 v = {0.f, 0.f, 0.f, 0.f};
    float ss = 0.f;
    if (t < 240) {
      v = *reinterpret_cast<const float4*>(&xr[t * 4]);
      ss = v.x * v.x + v.y * v.y + v.z * v.z + v.w * v.w;
    }
#pragma unroll
    for (int off = 32; off; off >>= 1) ss += __shfl_down(ss, off);
    __shared__ float red[4];
    __shared__ float s_scale;
    if ((t & 63) == 0) red[t >> 6] = ss;
    __syncthreads();
    if (t == 0) {
      float tot = red[0] + red[1] + red[2] + red[3];
      s_scale = rsqrtf(tot * (1.f / 960.f) + EPS);
    }
    __syncthreads();
    if (t < 240) {
      const float sc = s_scale;
      const float4 gv = *reinterpret_cast<const float4*>(&g1[t * 4]);
      ushort4 o;
      o.x = f2bfu(v.x * sc * gv.x);
      o.y = f2bfu(v.y * sc * gv.y);
      o.z = f2bfu(v.z * sc * gv.z);
      o.w = f2bfu(v.w * sc * gv.w);
      *reinterpret_cast<ushort4*>(&nb[(size_t)row * 960 + t * 4]) = o;
    }
  }
}

// ---------------- rmsfuse: x2 = sum(P)+x; dual norm (g2->nbF, g1->nbK) ------
__launch_bounds__(256)
__global__ void rmsfuse_k(const __half* __restrict__ P, const float* __restrict__ x,
                          const float* __restrict__ g1, const float* __restrict__ g2,
                          float* __restrict__ x2, bf16* __restrict__ nbF,
                          bf16* __restrict__ nbK) {
  const int row = blockIdx.x;
  const int t = threadIdx.x;
  float4 v = {0.f, 0.f, 0.f, 0.f};
  float ss = 0.f;
  if (t < 240) {
    const size_t e = (size_t)row * 960 + t * 4;
    v = *reinterpret_cast<const float4*>(&x[e]);
#pragma unroll
    for (int s = 0; s < 4; ++s) {
      ushort4 pa = *reinterpret_cast<const ushort4*>(&P[(size_t)s * 1966080 + e]);
      v.x += hu2f(pa.x); v.y += hu2f(pa.y); v.z += hu2f(pa.z); v.w += hu2f(pa.w);
    }
    ss = v.x * v.x + v.y * v.y + v.z * v.z + v.w * v.w;
  }
#pragma unroll
  for (int off = 32; off; off >>= 1) ss += __shfl_down(ss, off);
  __shared__ float red[4];
  __shared__ float s_scale;
  if ((t & 63) == 0) red[t >> 6] = ss;
  __syncthreads();
  if (t == 0) {
    float tot = red[0] + red[1] + red[2] + red[3];
    s_scale = rsqrtf(tot * (1.f / 960.f) + EPS);
  }
  __syncthreads();
  if (t < 240) {
    const size_t e = (size_t)row * 960 + t * 4;
    const float sc = s_scale;
    *reinterpret_cast<float4*>(&x2[e]) = v;
    const float4 gv2 = *reinterpret_cast<const float4*>(&g2[t * 4]);
    const float4 gv1 = *reinterpret_cast<const float4*>(&g1[t * 4]);
    ushort4 oF, oK;
    oF.x = f2bfu(v.x * sc * gv2.x); oF.y = f2bfu(v.y * sc * gv2.y);
    oF.z = f2bfu(v.z * sc * gv2.z); oF.w = f2bfu(v.w * sc * gv2.w);
    oK.x = f2bfu(v.x * sc * gv1.x); oK.y = f2bfu(v.y * sc * gv1.y);
    oK.z = f2bfu(v.z * sc * gv1.z); oK.w = f2bfu(v.w * sc * gv1.w);
    *reinterpret_cast<ushort4*>(&nbF[e]) = oF;
    *reinterpret_cast<ushort4*>(&nbK[e]) = oK;
  }
}

// ---------------- FFN GEMM 128x128 (natural dispatch), SwiGLU epilogue ------
__launch_bounds__(256)
__global__ void gemm_ffn(const bf16* __restrict__ A, const bf16* __restrict__ BT,
                         bf16* __restrict__ actb) {
  __shared__ __align__(16) bf16 sA[2][4096];
  __shared__ __align__(16) bf16 sB[2][4096];
  const int t = threadIdx.x, w = t >> 6, lane = t & 63;
  const int lg = lane >> 4, lr = lane & 15;
  const int wm = w >> 1, wn = w & 1;
  const int m0 = blockIdx.y * 128, n0 = blockIdx.x * 128;
  f32x4 acc[4][4] = {};
  gemm_core128(A, BT, 960, 0, 30, m0, n0, sA, sB, acc);

  const int colbase = n0 + wn * 64;
#pragma unroll
  for (int mi = 0; mi < 4; ++mi) {
    const int row = m0 + wm * 64 + mi * 16 + lg * 4;
#pragma unroll
    for (int p = 0; p < 2; ++p) {
      const int oc = ((colbase >> 5) + p) * 16 + lr;
#pragma unroll
      for (int r = 0; r < 4; ++r) {
        float gf = acc[mi][2 * p][r], uf = acc[mi][2 * p + 1][r];
        float s = gf / (1.f + __expf(-gf));
        actb[(size_t)(row + r) * 2560 + oc] = __float2bfloat16(s * uf);
      }
    }
  }
}

// ---------------- split-K GEMM -> fp16 partials (R11 structure) -------------
__launch_bounds__(256)
__global__ void gemm_skp(const bf16* __restrict__ A, const bf16* __restrict__ BT,
                         __half* __restrict__ P, int N, int K, int nsteps, int spl) {
  __shared__ __align__(16) bf16 sA[2][4096];
  __shared__ __align__(16) bf16 sB[2][4096];
  const int nx = gridDim.x, ny = gridDim.y;
  const int total = nx * ny * gridDim.z;
  const int lid = blockIdx.x + nx * (blockIdx.y + ny * blockIdx.z);
  const int cpx = total >> 3;
  const int sid = (lid & 7) * cpx + (lid >> 3);
  const int bx = sid % nx, by = (sid / nx) % ny, bz = sid / (nx * ny);
  const int t = threadIdx.x, w = t >> 6, lane = t & 63;
  const int lg = lane >> 4, lr = lane & 15;
  const int wm = w >> 1, wn = w & 1;
  const int m0 = by * 128, n0 = bx * 128;
  const int ks0 = bz * spl, ks1 = min(ks0 + spl, nsteps);
  f32x4 acc[4][4] = {};
  gemm_core128(A, BT, K, ks0, ks1, m0, n0, sA, sB, acc);

  __half* Ps = P + (size_t)bz * 2048 * N;
#pragma unroll
  for (int mi = 0; mi < 4; ++mi) {
    const int row = m0 + wm * 64 + mi * 16 + lg * 4;
#pragma unroll
    for (int ni = 0; ni < 4; ++ni) {
      const int col = n0 + wn * 64 + ni * 16 + lr;
      if (col < N) {
#pragma unroll
        for (int r = 0; r < 4; ++r)
          Ps[(size_t)(row + r) * N + col] = __float2half(acc[mi][ni][r]);
      }
    }
  }
}

// ---------------- final reduce: out = sum(Q)+x2 | kv split from R -----------
__launch_bounds__(256)
__global__ void reduce_final_k(const __half* __restrict__ Q, const float* __restrict__ x2,
                               const __half* __restrict__ R, float* __restrict__ out) {
  const int i = blockIdx.x * 256 + threadIdx.x;
  const int n1 = 491520;   // 1,966,080/4
  const int n2 = 327680;   // 1,310,720/4
  if (i < n1) {
    const size_t e = (size_t)i * 4;
    float4 v = *reinterpret_cast<const float4*>(&x2[e]);
#pragma unroll
    for (int s = 0; s < 4; ++s) {
      ushort4 q = *reinterpret_cast<const ushort4*>(&Q[(size_t)s * 1966080 + e]);
      v.x += hu2f(q.x); v.y += hu2f(q.y); v.z += hu2f(q.z); v.w += hu2f(q.w);
    }
    *reinterpret_cast<float4*>(&out[e]) = v;
  } else if (i < n1 + n2) {
    const size_t e = (size_t)(i - n1) * 4;
    float4 v = {0.f, 0.f, 0.f, 0.f};
#pragma unroll
    for (int s = 0; s < 4; ++s) {
      ushort4 q = *reinterpret_cast<const ushort4*>(&R[(size_t)s * 1310720 + e]);
      v.x += hu2f(q.x); v.y += hu2f(q.y); v.z += hu2f(q.z); v.w += hu2f(q.w);
    }
    const int rr = (int)(e / 640), cc = (int)(e % 640);
    float* dst = (cc < 320) ? out + 1966080 + (size_t)rr * 320 + cc
                            : out + 1966080 + 655360 + (size_t)rr * 320 + (cc - 320);
    *reinterpret_cast<float4*>(dst) = v;
  }
}

// ---------------- QKV GEMM 64x128, fused RoPE + fragment-order K/V ----------
__launch_bounds__(256)
__global__ void gemm_qkv(const bf16* __restrict__ A, const bf16* __restrict__ BT,
                         const float2* __restrict__ cstab, bf16* __restrict__ qr,
                         bf16* __restrict__ kr2, bf16* __restrict__ vTb2) {
  const int N = 1600, K = 960;
  __shared__ __align__(16) bf16 sA[2][64 * 32];
  __shared__ __align__(16) bf16 sB[2][128 * 32];
  const int t = threadIdx.x, w = t >> 6, lane = t & 63;
  const int lg = lane >> 4, lr = lane & 15;
  const int wm = w >> 1, wn = w & 1;
  const int m0 = blockIdx.y * 64, n0 = blockIdx.x * 128;
  f32x4 acc[2][4] = {};
  const int nsteps = K / 32;

  const int cA = t, cB0 = t, cB1 = t + 256;
  const bf16* pA = A + (size_t)(m0 + (cA >> 2)) * K + (cA & 3) * 8;
  int brow0 = n0 + (cB0 >> 2); if (brow0 >= N) brow0 = N - 1;
  int brow1 = n0 + (cB1 >> 2); if (brow1 >= N) brow1 = N - 1;
  const bf16* pB0 = BT + (size_t)brow0 * K + (cB0 & 3) * 8;
  const bf16* pB1 = BT + (size_t)brow1 * K + (cB1 & 3) * 8;
  auto stage = [&](int buf) {
    gload_lds16(pA, &sA[buf][cA * 8]);
    gload_lds16(pB0, &sB[buf][cB0 * 8]);
    gload_lds16(pB1, &sB[buf][cB1 * 8]);
    pA += 32; pB0 += 32; pB1 += 32;
  };

  stage(0);
  __syncthreads();
  int cur = 0;
  for (int ks = 0; ks < nsteps; ++ks) {
    if (ks + 1 < nsteps) stage(cur ^ 1);
    bf16x8 af[2], bfr[4];
#pragma unroll
    for (int mi = 0; mi < 2; ++mi)
      af[mi] = *reinterpret_cast<const bf16x8*>(&sA[cur][(wm * 32 + mi * 16 + lr) * 32 + lg * 8]);
#pragma unroll
    for (int ni = 0; ni < 4; ++ni)
      bfr[ni] = *reinterpret_cast<const bf16x8*>(&sB[cur][(wn * 64 + ni * 16 + lr) * 32 + lg * 8]);
#pragma unroll
    for (int mi = 0; mi < 2; ++mi)
#pragma unroll
      for (int ni = 0; ni < 4; ++ni)
        acc[mi][ni] = __builtin_amdgcn_mfma_f32_16x16x32_bf16(af[mi], bfr[ni], acc[mi][ni], 0, 0, 0);
    __syncthreads();
    cur ^= 1;
  }

  const int colbase = n0 + wn * 64;
  if (colbase >= 1600) return;
  if (colbase < 960) {
#pragma unroll
    for (int mi = 0; mi < 2; ++mi) {
      const int row = m0 + wm * 32 + mi * 16 + lg * 4;
#pragma unroll
      for (int ni = 0; ni < 2; ++ni) {
        const int d = ni * 16 + lr;
#pragma unroll
        for (int r = 0; r < 4; ++r) {
          const int pos = row + r;
          float2 cs = cstab[pos * 32 + d];
          float x1 = acc[mi][ni][r], x2 = acc[mi][ni + 2][r];
          qr[(size_t)pos * 960 + colbase + d] =
              __float2bfloat16((x1 * cs.x - x2 * cs.y) * QSCL);
          qr[(size_t)pos * 960 + colbase + d + 32] =
              __float2bfloat16((x2 * cs.x + x1 * cs.y) * QSCL);
        }
      }
    }
  } else if (colbase < 1280) {
    const int cb = colbase - 960;
    const int kvh = cb >> 6;
#pragma unroll
    for (int mi = 0; mi < 2; ++mi) {
      const int row = m0 + wm * 32 + mi * 16 + lg * 4;
#pragma unroll
      for (int ni = 0; ni < 2; ++ni) {
        const int d = ni * 16 + lr;
#pragma unroll
        for (int r = 0; r < 4; ++r) {
          const int pos = row + r;
          float2 cs = cstab[pos * 32 + d];
          float v1 = acc[mi][ni][r] * cs.x - acc[mi][ni + 2][r] * cs.y;
          float v2 = acc[mi][ni + 2][r] * cs.x + acc[mi][ni][r] * cs.y;
          const size_t blk = ((size_t)(pos >> 5) * 5 + kvh) * 2048;
          const int dl1 = d, dl2 = d + 32;
          kr2[blk + (size_t)(((dl1 >> 4) << 6) + (((dl1 >> 3) & 1) << 5) + (pos & 31)) * 8 + (dl1 & 7)] =
              __float2bfloat16(v1);
          kr2[blk + (size_t)(((dl2 >> 4) << 6) + (((dl2 >> 3) & 1) << 5) + (pos & 31)) * 8 + (dl2 & 7)] =
              __float2bfloat16(v2);
        }
      }
    }
  } else {
#pragma unroll
    for (int mi = 0; mi < 2; ++mi) {
      const int row = m0 + wm * 32 + mi * 16 + lg * 4;
#pragma unroll
      for (int ni = 0; ni < 4; ++ni) {
        const int vc = colbase - 1280 + ni * 16 + lr;
        ushort4 pk;
        pk.x = f2bfu(acc[mi][ni][0]);
        pk.y = f2bfu(acc[mi][ni][1]);
        pk.z = f2bfu(acc[mi][ni][2]);
        pk.w = f2bfu(acc[mi][ni][3]);
        const int db = (vc >> 5) & 1, dq = vc & 31;
        const int pb = (row >> 4) & 1, h2 = (row >> 3) & 1;
        const size_t blk = ((size_t)(row >> 5) * 5 + (vc >> 6)) * 2048;
        *reinterpret_cast<ushort4*>(
            &vTb2[blk + (size_t)(((db * 2 + pb) << 6) + (h2 << 5) + dq) * 8 + (row & 7)]) = pk;
      }
    }
  }
}

// ---------------- persistent-wave flash attention (1 item / block) ----------
__launch_bounds__(64)
__global__ void attn_part8(const bf16* __restrict__ q, const bf16* __restrict__ kr2,
                           const bf16* __restrict__ vTb2, const int* __restrict__ items,
                           bf16* __restrict__ pacc, float* __restrict__ pml) {
  const int lane = threadIdx.x & 63;
  const int ql = lane & 31, hi = lane >> 5;
  const int kvoff = 4 * hi;

  {
    const int it = blockIdx.x;
    const int v = items[it];
    const int qt = v & 255, head = (v >> 8) & 255, c = v >> 16;
    const int q0 = qt * 32;
    const int kvh = head / 3;
    const int t0 = c * 8, t1 = min(t0 + 8, qt + 1);
    const int qrow = q0 + ql;

    bf16x8 qf0 = *reinterpret_cast<const bf16x8*>(&q[(size_t)(q0 + ql) * 960 + head * 64 + hi * 8]);
    bf16x8 qf1 = *reinterpret_cast<const bf16x8*>(&q[(size_t)(q0 + ql) * 960 + head * 64 + 16 + hi * 8]);
    bf16x8 qf2 = *reinterpret_cast<const bf16x8*>(&q[(size_t)(q0 + ql) * 960 + head * 64 + 32 + hi * 8]);
    bf16x8 qf3 = *reinterpret_cast<const bf16x8*>(&q[(size_t)(q0 + ql) * 960 + head * 64 + 48 + hi * 8]);

    f32x16 acc0 = {}, acc1 = {};
    float mrun = -1e30f, lrun = 0.f;
    const bf16* kp = kr2 + ((size_t)t0 * 5 + kvh) * 2048 + (hi * 32 + ql) * 8;
    const bf16* vp = vTb2 + ((size_t)t0 * 5 + kvh) * 2048 + (hi * 32 + ql) * 8;

    for (int kb = t0; kb < t1; ++kb) {
      bf16x8 kc0 = *reinterpret_cast<const bf16x8*>(kp);
      bf16x8 kc1 = *reinterpret_cast<const bf16x8*>(kp + 512);
      bf16x8 kc2 = *reinterpret_cast<const bf16x8*>(kp + 1024);
      bf16x8 kc3 = *reinterpret_cast<const bf16x8*>(kp + 1536);
      bf16x8 vc0 = *reinterpret_cast<const bf16x8*>(vp);
      bf16x8 vc1 = *reinterpret_cast<const bf16x8*>(vp + 512);
      bf16x8 vc2 = *reinterpret_cast<const bf16x8*>(vp + 1024);
      bf16x8 vc3 = *reinterpret_cast<const bf16x8*>(vp + 1536);

      __builtin_amdgcn_s_setprio(1);
      f32x16 sa = {}, sb = {};
      sa = __builtin_amdgcn_mfma_f32_32x32x16_bf16(kc0, qf0, sa, 0, 0, 0);
      sb = __builtin_amdgcn_mfma_f32_32x32x16_bf16(kc1, qf1, sb, 0, 0, 0);
      sa = __builtin_amdgcn_mfma_f32_32x32x16_bf16(kc2, qf2, sa, 0, 0, 0);
      sb = __builtin_amdgcn_mfma_f32_32x32x16_bf16(kc3, qf3, sb, 0, 0, 0);
      __builtin_amdgcn_s_setprio(0);

      if (kb == qt) {
        const int kvb = kb * 32;
#pragma unroll
        for (int r = 0; r < 16; ++r) {
          const int kv = kvb + kvoff + (r & 3) + 8 * (r >> 2);
          float sv = sa[r] + sb[r];
          sa[r] = (kv > qrow) ? -1e30f : sv;
        }
      } else {
#pragma unroll
        for (int r = 0; r < 16; ++r) sa[r] += sb[r];
      }

      float m0_ = fmaxf(fmaxf(sa[0], sa[1]), fmaxf(sa[2], sa[3]));
      float m1_ = fmaxf(fmaxf(sa[4], sa[5]), fmaxf(sa[6], sa[7]));
      float m2_ = fmaxf(fmaxf(sa[8], sa[9]), fmaxf(sa[10], sa[11]));
      float m3_ = fmaxf(fmaxf(sa[12], sa[13]), fmaxf(sa[14], sa[15]));
      float tm = fmaxf(fmaxf(m0_, m1_), fmaxf(m2_, m3_));
      tm = fmaxf(tm, __shfl_xor(tm, 32));
      if (__any(tm > mrun + 11.5f)) {
        const float mn = fmaxf(mrun, tm);
        const float ef = exp2f(mrun - mn);
        mrun = mn;
#pragma unroll
        for (int r = 0; r < 16; ++r) { acc0[r] *= ef; acc1[r] *= ef; }
        lrun *= ef;
      }
#pragma unroll
      for (int r = 0; r < 16; ++r) sa[r] = exp2f(sa[r] - mrun);
      float t0_ = (sa[0] + sa[1]) + (sa[2] + sa[3]);
      float t1_ = (sa[4] + sa[5]) + (sa[6] + sa[7]);
      float t2_ = (sa[8] + sa[9]) + (sa[10] + sa[11]);
      float t3_ = (sa[12] + sa[13]) + (sa[14] + sa[15]);
      float ts = (t0_ + t1_) + (t2_ + t3_);
      ts += __shfl_xor(ts, 32);
      lrun += ts;

      unsigned int a0 = cvtpk(sa[0], sa[1]), a1 = cvtpk(sa[2], sa[3]);
      unsigned int a2 = cvtpk(sa[4], sa[5]), a3 = cvtpk(sa[6], sa[7]);
      unsigned int b0 = cvtpk(sa[8], sa[9]), b1 = cvtpk(sa[10], sa[11]);
      unsigned int b2 = cvtpk(sa[12], sa[13]), b3 = cvtpk(sa[14], sa[15]);
      asm volatile("v_permlane32_swap_b32 %0, %1" : "+v"(a0), "+v"(a2));
      asm volatile("v_permlane32_swap_b32 %0, %1" : "+v"(a1), "+v"(a3));
      asm volatile("v_permlane32_swap_b32 %0, %1" : "+v"(b0), "+v"(b2));
      asm volatile("v_permlane32_swap_b32 %0, %1" : "+v"(b1), "+v"(b3));
      union { unsigned int u[4]; bf16x8 v; } f0, f1;
      f0.u[0] = a0; f0.u[1] = a1; f0.u[2] = a2; f0.u[3] = a3;
      f1.u[0] = b0; f1.u[1] = b1; f1.u[2] = b2; f1.u[3] = b3;

      __builtin_amdgcn_s_setprio(1);
      acc0 = __builtin_amdgcn_mfma_f32_32x32x16_bf16(vc0, f0.v, acc0, 0, 0, 0);
      acc1 = __builtin_amdgcn_mfma_f32_32x32x16_bf16(vc2, f0.v, acc1, 0, 0, 0);
      acc0 = __builtin_amdgcn_mfma_f32_32x32x16_bf16(vc1, f1.v, acc0, 0, 0, 0);
      acc1 = __builtin_amdgcn_mfma_f32_32x32x16_bf16(vc3, f1.v, acc1, 0, 0, 0);
      __builtin_amdgcn_s_setprio(0);

      kp += 5 * 2048;
      vp += 5 * 2048;
    }

    const size_t base = (size_t)it * 2048;
#pragma unroll
    for (int r = 0; r < 16; ++r) {
      const int row = (r & 3) + 8 * (r >> 2) + kvoff;
      pacc[base + (size_t)row * 32 + ql] = __float2bfloat16(acc0[r]);
      pacc[base + (size_t)(row + 32) * 32 + ql] = __float2bfloat16(acc1[r]);
    }
    const size_t mb = (size_t)it * 64;
    if (!hi) {
      pml[mb + ql * 2] = mrun;
      pml[mb + ql * 2 + 1] = lrun;
    }
  }
}

// ---------------- attention merge (exp2 domain, triangular slots) -----------
__launch_bounds__(256)
__global__ void attn_merge4(const bf16* __restrict__ pacc, const float* __restrict__ pml,
                            bf16* __restrict__ ctx) {
  const int qt = blockIdx.x, head = blockIdx.y;
  const int a = qt >> 3, bq = qt & 7;
  const int psum = qt + 8 * (a * (a - 1) / 2) + a * bq;
  const int slot0 = head * 288 + psum;
  const int nch = (qt >> 3) + 1;
  const size_t base = (size_t)slot0 * 2048;
  const size_t mb = (size_t)slot0 * 64;
  __shared__ float smem[32][65];
  for (int i = threadIdx.x; i < 2048; i += 256) {
    const int qi = i & 31, d = i >> 5;
    float m = -1e30f;
    for (int c = 0; c < nch; ++c) m = fmaxf(m, pml[mb + c * 64 + qi * 2]);
    float lsum = 0.f, o = 0.f;
    for (int c = 0; c < nch; ++c) {
      float e = exp2f(pml[mb + c * 64 + qi * 2] - m);
      lsum += pml[mb + c * 64 + qi * 2 + 1] * e;
      o += __bfloat162float(pacc[base + c * 2048 + d * 32 + qi]) * e;
    }
    smem[qi][d] = o / lsum;
  }
  __syncthreads();
  for (int i = threadIdx.x; i < 2048; i += 256) {
    const int qi = i >> 6, d = i & 63;
    ctx[(size_t)(qt * 32 + qi) * 960 + head * 64 + d] = __float2bfloat16(smem[qi][d]);
  }
}

// ---------------- launch ----------------------------------------------------
extern "C" void kernel_launch(void* const* d_in, const int* in_sizes, int n_in,
                              void* d_out, int out_size, void* d_ws, size_t ws_size,
                              hipStream_t stream) {
  const float* x  = (const float*)d_in[0];
  const float* wq = (const float*)d_in[1];
  const float* wk = (const float*)d_in[2];
  const float* wv = (const float*)d_in[3];
  const float* wo = (const float*)d_in[4];
  const float* wg = (const float*)d_in[5];
  const float* wu = (const float*)d_in[6];
  const float* wd = (const float*)d_in[7];
  const float* g1 = (const float*)d_in[8];
  const float* g2 = (const float*)d_in[9];
  float* out = (float*)d_out;

  char* ws = (char*)d_ws;
  bf16*   wT    = (bf16*)ws;                       // 0 .. 20,111,360
  bf16*   pacc  = (bf16*)(ws + 20111360);          // 17,694,720 (attn partials)
  __half* Ppart = (__half*)(ws + 20111360);        // 15,728,640 (wo/wd partials, post-merge)
  float*  pml   = (float*)(ws + 37806080);         // 1,105,920 (ends 38,912,000)
  bf16*   qr    = (bf16*)(ws + 38912000);          // 3,932,160
  bf16*   kr2   = (bf16*)(ws + 42844160);          // 1,310,720
  bf16*   vTb2  = (bf16*)(ws + 44154880);          // 1,310,720
  bf16*   ctx   = (bf16*)(ws + 45465600);          // 3,932,160 (ends 49,397,760)
  bf16*   actb  = (bf16*)(ws + 38912000);          // 10,485,760 (overlays qr..ctx, post-wo)
  __half* Rpart = (__half*)(ws + 38912000);        // 10,485,760 (overlays actb, post-wd)
  bf16*   nbF   = (bf16*)(ws + 49397760);          // 3,932,160
  bf16*   nbK   = (bf16*)(ws + 53329920);          // 3,932,160
  float*  x2    = (float*)(ws + 57262080);         // 7,864,320 (ends 65,126,400)
  float2* cst   = (float2*)(ws + 65126400);        // 524,288
  int*    items = (int*)(ws + 65650688);           // 17,280 (total ~65.7 MB)

  bf16* wqkvT = wT;            // 1600 x 960 (q|k|v rows)
  bf16* wkT  = wT + 921600;    // 640 x 960 (k|v rows) for kv GEMM
  bf16* woT  = wT + 1536000;   // 1024 x 960 (rows 960+ pad)
  bf16* wguT = wT + 2519040;   // 5120 x 960 interleaved [gate16|up16]
  bf16* wdT  = wT + 7434240;   // 1024 x 2560 (rows 960+ pad)

  dim3 blk(256);
  prep2_k<<<4708, blk, 0, stream>>>(wq, wk, wv, wo, wg, wu, wd,
                                    wqkvT, woT, wguT, wdT, cst, items, x, g1, nbF);
  gemm_qkv<<<dim3(13, 32), blk, 0, stream>>>(nbF, wqkvT, cst, qr, kr2, vTb2);
  attn_part8<<<4320, dim3(64), 0, stream>>>(qr, kr2, vTb2, items, pacc, pml);
  attn_merge4<<<dim3(64, 15), blk, 0, stream>>>(pacc, pml, ctx);
  gemm_skp<<<dim3(8, 16, 4), blk, 0, stream>>>(ctx, woT, Ppart, 960, 960, 30, 8);
  rmsfuse_k<<<2048, blk, 0, stream>>>(Ppart, x, g1, g2, x2, nbF, nbK);
  gemm_ffn<<<dim3(40, 16), blk, 0, stream>>>(nbF, wguT, actb);
  gemm_skp<<<dim3(8, 16, 4), blk, 0, stream>>>(actb, wdT, Ppart, 960, 2560, 80, 20);
  gemm_skp<<<dim3(5, 16, 4), blk, 0, stream>>>(nbK, wkT, Rpart, 640, 960, 30, 8);
  reduce_final_k<<<3200, blk, 0, stream>>>(Ppart, x2, Rpart, out);
}